// Round 8
// baseline (79169.147 us; speedup 1.0000x reference)
//
#include <hip/hip_runtime.h>
#include <math.h>

#define TPB 256
#define SMLSIZ 25
#define D_EPS    1.1102230246251565e-16
#define D_SAFMIN 2.2250738585072014e-308
#define CMDMAX 8192
#define SCHUNK 64

// ============================ small LAPACK helpers ============================
__device__ __forceinline__ double d_sign(double a, double b){
  double aa = fabs(a);
  return (b >= 0.0) ? aa : -aa;
}
__device__ __forceinline__ double dlapy2(double x, double y){
  double xa = fabs(x), ya = fabs(y);
  double w = fmax(xa, ya), z = fmin(xa, ya);
  if (z == 0.0) return w;
  double t = z / w;
  return w * sqrt(1.0 + t*t);
}
// LAPACK >= 3.10 dlartg
__device__ void dlartg(double f, double g, double* cs, double* sn, double* r){
  if (g == 0.0) { *cs = 1.0; *sn = 0.0; *r = f; return; }
  if (f == 0.0) { *cs = 0.0; *sn = (g >= 0.0) ? 1.0 : -1.0; *r = fabs(g); return; }
  double f1 = fabs(f), g1 = fabs(g);
  double rtmin = sqrt(D_SAFMIN);
  double rtmax = sqrt(1.0/(2.0*D_SAFMIN));
  if (f1 > rtmin && f1 < rtmax && g1 > rtmin && g1 < rtmax) {
    double d = sqrt(f*f + g*g);
    *cs = f1 / d;
    double rr = (f >= 0.0) ? d : -d;
    *sn = g / rr;
    *r = rr;
  } else {
    double safmax = 1.0/D_SAFMIN;
    double u = fmin(safmax, fmax(fmax(D_SAFMIN, f1), g1));
    double fs = f/u, gs = g/u;
    double d = sqrt(fs*fs + gs*gs);
    *cs = fabs(fs)/d;
    double rr = (f >= 0.0) ? d : -d;
    *sn = gs / rr;
    *r = rr * u;
  }
}
__device__ void dlaev2(double a, double b, double c,
                       double* rt1, double* rt2, double* cs1, double* sn1){
  double sm = a + c, df = a - c, adf = fabs(df), tb = b + b, ab = fabs(tb);
  double acmx, acmn;
  if (fabs(a) > fabs(c)) { acmx = a; acmn = c; } else { acmx = c; acmn = a; }
  double rt;
  if (adf > ab)      { double t = ab/adf; rt = adf*sqrt(1.0+t*t); }
  else if (adf < ab) { double t = adf/ab; rt = ab*sqrt(1.0+t*t); }
  else               rt = ab*sqrt(2.0);
  int sgn1;
  if (sm < 0.0)      { *rt1 = 0.5*(sm-rt); sgn1 = -1; *rt2 = (acmx / *rt1)*acmn - (b / *rt1)*b; }
  else if (sm > 0.0) { *rt1 = 0.5*(sm+rt); sgn1 =  1; *rt2 = (acmx / *rt1)*acmn - (b / *rt1)*b; }
  else               { *rt1 = 0.5*rt; *rt2 = -0.5*rt; sgn1 = 1; }
  int sgn2; double cs;
  if (df >= 0.0) { cs = df + rt; sgn2 = 1; } else { cs = df - rt; sgn2 = -1; }
  double acs = fabs(cs);
  if (acs > ab) {
    double ct = -tb/cs;
    *sn1 = 1.0/sqrt(1.0+ct*ct);
    *cs1 = ct * (*sn1);
  } else {
    if (ab == 0.0) { *cs1 = 1.0; *sn1 = 0.0; }
    else { double tn = -cs/tb; *cs1 = 1.0/sqrt(1.0+tn*tn); *sn1 = tn * (*cs1); }
  }
  if (sgn1 == sgn2) { double tn = *cs1; *cs1 = -(*sn1); *sn1 = tn; }
}
__device__ void dlamrg(int n1, int n2, const double* a, int s1, int s2, int* idx){
  int n1sv = n1, n2sv = n2;
  int ind1 = (s1 > 0) ? 0 : n1-1;
  int ind2 = (s2 > 0) ? n1 : n1+n2-1;
  int i = 0;
  while (n1sv > 0 && n2sv > 0) {
    if (a[ind1] <= a[ind2]) { idx[i++] = ind1; ind1 += s1; n1sv--; }
    else                    { idx[i++] = ind2; ind2 += s2; n2sv--; }
  }
  while (n1sv > 0) { idx[i++] = ind1; ind1 += s1; n1sv--; }
  while (n2sv > 0) { idx[i++] = ind2; ind2 += s2; n2sv--; }
}

__device__ void my_laed5(int i, const double* d, const double* z, double rho,
                         double* delta, double* lam){
  double del = d[1]-d[0];
  if (i == 0) {
    double w = 1.0 + 2.0*rho*(z[1]*z[1]-z[0]*z[0])/del;
    if (w > 0.0) {
      double b = del + rho*(z[0]*z[0]+z[1]*z[1]);
      double c = rho*z[0]*z[0]*del;
      double tau = 2.0*c/(b+sqrt(fabs(b*b-4.0*c)));
      *lam = d[0] + tau;
      delta[0] = -z[0]/tau;
      delta[1] =  z[1]/(del-tau);
    } else {
      double b = -del + rho*(z[0]*z[0]+z[1]*z[1]);
      double c = rho*z[1]*z[1]*del;
      double tau;
      if (b > 0.0) tau = -2.0*c/(b+sqrt(b*b+4.0*c));
      else         tau = (b - sqrt(b*b+4.0*c))/2.0;
      *lam = d[1] + tau;
      delta[0] = -z[0]/(del+tau);
      delta[1] = -z[1]/tau;
    }
    double temp = dlapy2(delta[0], delta[1]);
    delta[0] /= temp; delta[1] /= temp;
  } else {
    double b = -del + rho*(z[0]*z[0]+z[1]*z[1]);
    double c = rho*z[1]*z[1]*del;
    double tau;
    if (b > 0.0) tau = (b+sqrt(b*b+4.0*c))/2.0;
    else         tau = 2.0*c/(-b+sqrt(b*b+4.0*c));
    *lam = d[1] + tau;
    delta[0] = -z[0]/(del+tau);
    delta[1] = -z[1]/tau;
    double temp = dlapy2(delta[0], delta[1]);
    delta[0] /= temp; delta[1] /= temp;
  }
}
__device__ void my_laed4(int k, int j, const double* dl, const double* w, double rho,
                         double* delta, double* lam){
  if (k == 1) { *lam = dl[0] + rho*w[0]*w[0]; delta[0] = 1.0; return; }
  if (k == 2) { my_laed5(j, dl, w, rho, delta, lam); return; }
  int base; double a, b;
  if (j < k-1) {
    double dj = dl[j], dj1 = dl[j+1];
    double mid = 0.5*(dj+dj1);
    double fm = 1.0;
#pragma unroll 4
    for (int i = 0; i < k; i++) fm += rho*w[i]*w[i]/(dl[i]-mid);
    if (fm >= 0.0) { base = j;   a = 0.0;      b = mid - dj;  }
    else           { base = j+1; a = mid - dj1; b = 0.0;      }
  } else {
    base = k-1;
    double zz = 0.0;
#pragma unroll 4
    for (int i = 0; i < k; i++) zz += w[i]*w[i];
    a = 0.0; b = rho*zz;
    for (int t = 0; t < 64; t++) {
      double g = 1.0;
#pragma unroll 4
      for (int i = 0; i < k; i++) g += rho*w[i]*w[i]/((dl[i]-dl[base]) - b);
      if (g >= 0.0) break;
      b *= 2.0;
    }
  }
  for (int it = 0; it < 140; it++) {
    double m = 0.5*(a+b);
    if (m == a || m == b) break;
    double g = 1.0;
#pragma unroll 4
    for (int i = 0; i < k; i++) g += rho*w[i]*w[i]/((dl[i]-dl[base]) - m);
    if (g >= 0.0) b = m; else a = m;
  }
  double tau = 0.5*(a+b);
  *lam = dl[base] + tau;
#pragma unroll 4
  for (int i = 0; i < k; i++) delta[i] = (dl[i]-dl[base]) - tau;
}

// ============================ STEQR scan (serial, rotation recorder) ============================
struct Cmd { double c, s; int a, b; };   // b<0: rotation on cols (a,a+1); else swap cols a,b

#define REC_CMD(CC,SS,AA,BB) do{ if (ncmd < cmax){ cbuf[ncmd].c=(CC); cbuf[ncmd].s=(SS); cbuf[ncmd].a=(AA); cbuf[ncmd].b=(BB);} ncmd++; }while(0)

__device__ int steqr_scan(int m, double* sd_, double* se_, Cmd* cbuf, int cmax){
  int ncmd = 0;
  const double eps = D_EPS, eps2 = D_EPS*D_EPS, safmin = D_SAFMIN;
  const double ssfmax = sqrt(1.7976931348623157e308)/3.0;
  const double ssfmin = sqrt(D_SAFMIN)/(D_EPS*D_EPS);
  int nmaxit = m*30, jtot = 0;
  int l1 = 0;
  bool noSort = false;
  while (1) {
    if (l1 > m-1) break;
    if (l1 > 0) se_[l1-1] = 0.0;
    int mm = m-1;
    for (int mi = l1; mi <= m-2; mi++) {
      double tst = fabs(se_[mi]);
      if (tst == 0.0) { mm = mi; break; }
      if (tst <= (sqrt(fabs(sd_[mi]))*sqrt(fabs(sd_[mi+1])))*eps) { se_[mi] = 0.0; mm = mi; break; }
    }
    int l = l1, lsv = l, lend = mm, lendsv = lend;
    l1 = mm+1;
    if (lend == l) continue;
    double anorm = 0.0;
    for (int i = l; i <= lend; i++) anorm = fmax(anorm, fabs(sd_[i]));
    for (int i = l; i <  lend; i++) anorm = fmax(anorm, fabs(se_[i]));
    if (anorm == 0.0) continue;
    int iscale = 0;
    if (anorm > ssfmax) { iscale = 1; double f = ssfmax/anorm;
      for (int i = l; i <= lend; i++) sd_[i] *= f;
      for (int i = l; i <  lend; i++) se_[i] *= f; }
    else if (anorm < ssfmin) { iscale = 2; double f = ssfmin/anorm;
      for (int i = l; i <= lend; i++) sd_[i] *= f;
      for (int i = l; i <  lend; i++) se_[i] *= f; }
    if (fabs(sd_[lend]) < fabs(sd_[l])) { int t = l; l = lend; lend = t; }
    if (lend > l) {
      // QL
      while (1) {
        int mq = lend;
        if (l != lend) {
          for (int mi = l; mi <= lend-1; mi++) {
            double tst = se_[mi]*se_[mi];
            if (tst <= (eps2*fabs(sd_[mi]))*fabs(sd_[mi+1]) + safmin) { mq = mi; break; }
          }
        }
        if (mq < lend) se_[mq] = 0.0;
        double p = sd_[l];
        if (mq == l) { sd_[l] = p; l++; if (l <= lend) continue; break; }
        if (mq == l+1) {
          double rt1, rt2, cc, ss;
          dlaev2(sd_[l], se_[l], sd_[l+1], &rt1, &rt2, &cc, &ss);
          REC_CMD(cc, ss, l, -1);
          sd_[l] = rt1; sd_[l+1] = rt2; se_[l] = 0.0;
          l += 2; if (l <= lend) continue; break;
        }
        if (jtot == nmaxit) break;
        jtot++;
        double g = (sd_[l+1]-p)/(2.0*se_[l]);
        double r = dlapy2(g, 1.0);
        g = sd_[mq] - p + se_[l]/(g + d_sign(r, g));
        double ss = 1.0, cc = 1.0; p = 0.0;
        for (int i = mq-1; i >= l; i--) {
          double ff = ss*se_[i], bb = cc*se_[i];
          dlartg(g, ff, &cc, &ss, &r);
          if (i != mq-1) se_[i+1] = r;
          g = sd_[i+1] - p;
          r = (sd_[i]-g)*ss + 2.0*cc*bb;
          p = ss*r;
          sd_[i+1] = g + p;
          g = cc*r - bb;
          REC_CMD(cc, -ss, i, -1);
        }
        sd_[l] -= p; se_[l] = g;
      }
    } else {
      // QR
      while (1) {
        int mq = lend;
        if (l != lend) {
          for (int mi = l; mi >= lend+1; mi--) {
            double tst = se_[mi-1]*se_[mi-1];
            if (tst <= (eps2*fabs(sd_[mi]))*fabs(sd_[mi-1]) + safmin) { mq = mi; break; }
          }
        }
        if (mq > lend) se_[mq-1] = 0.0;
        double p = sd_[l];
        if (mq == l) { sd_[l] = p; l--; if (l >= lend) continue; break; }
        if (mq == l-1) {
          double rt1, rt2, cc, ss;
          dlaev2(sd_[l-1], se_[l-1], sd_[l], &rt1, &rt2, &cc, &ss);
          REC_CMD(cc, ss, l-1, -1);
          sd_[l-1] = rt1; sd_[l] = rt2; se_[l-1] = 0.0;
          l -= 2; if (l >= lend) continue; break;
        }
        if (jtot == nmaxit) break;
        jtot++;
        double g = (sd_[l-1]-p)/(2.0*se_[l-1]);
        double r = dlapy2(g, 1.0);
        g = sd_[mq] - p + se_[l-1]/(g + d_sign(r, g));
        double ss = 1.0, cc = 1.0; p = 0.0;
        for (int i = mq; i <= l-1; i++) {
          double ff = ss*se_[i], bb = cc*se_[i];
          dlartg(g, ff, &cc, &ss, &r);
          if (i != mq) se_[i-1] = r;
          g = sd_[i] - p;
          r = (sd_[i+1]-g)*ss + 2.0*cc*bb;
          p = ss*r;
          sd_[i] = g + p;
          g = cc*r - bb;
          REC_CMD(cc, ss, i, -1);
        }
        sd_[l] -= p; se_[l-1] = g;
      }
    }
    if (iscale == 1) { double f = anorm/ssfmax;
      for (int i = lsv; i <= lendsv; i++) sd_[i] *= f;
      for (int i = lsv; i <  lendsv; i++) se_[i] *= f; }
    else if (iscale == 2) { double f = anorm/ssfmin;
      for (int i = lsv; i <= lendsv; i++) sd_[i] *= f;
      for (int i = lsv; i <  lendsv; i++) se_[i] *= f; }
    if (jtot >= nmaxit) { noSort = true; break; }
  }
  if (!noSort) {
    for (int ii = 1; ii <= m-1; ii++) {
      int i = ii-1, kk = i; double p = sd_[i];
      for (int j = ii; j <= m-1; j++) if (sd_[j] < p) { kk = j; p = sd_[j]; }
      if (kk != i) {
        sd_[kk] = sd_[i]; sd_[i] = p;
        REC_CMD(0.0, 0.0, i, kk);
      }
    }
  }
  return (ncmd <= cmax) ? ncmd : cmax;
}

// apply one command to column-pair at row r (ld = column stride)
__device__ __forceinline__ void apply_cmd(const Cmd& cm, double* z, int ld, int r){
  if (cm.b < 0) {
    double t1 = z[(size_t)(cm.a+1)*ld + r];
    double t0 = z[(size_t)cm.a*ld + r];
    z[(size_t)(cm.a+1)*ld + r] = cm.c*t1 - cm.s*t0;
    z[(size_t)cm.a*ld + r]     = cm.s*t1 + cm.c*t0;
  } else {
    double t0 = z[(size_t)cm.a*ld + r];
    z[(size_t)cm.a*ld + r] = z[(size_t)cm.b*ld + r];
    z[(size_t)cm.b*ld + r] = t0;
  }
}

// ============================ STEQR (direct path: scan + chunked replay) ============================
template<int NT>
__device__ void dev_steqr(int m, double* sd_, double* se_, double* z, int ldz,
                          Cmd* cbuf, int* icom, Cmd* scmd){
  const int tid = threadIdx.x;
  for (int x = tid; x < m*m; x += NT) z[(size_t)(x/m)*ldz + (x%m)] = ((x/m) == (x%m)) ? 1.0 : 0.0;
  __syncthreads();
  if (m <= 1) return;
  if (tid == 0) icom[0] = steqr_scan(m, sd_, se_, cbuf, CMDMAX);
  __syncthreads();
  int ncmd = icom[0];
  for (int base = 0; base < ncmd; base += SCHUNK) {
    int cnt = ncmd - base; if (cnt > SCHUNK) cnt = SCHUNK;
    for (int q = tid; q < cnt; q += NT) scmd[q] = cbuf[base+q];
    __syncthreads();
    for (int r = tid; r < m; r += NT)
#pragma unroll 2
      for (int q = 0; q < cnt; q++) apply_cmd(scmd[q], z, ldz, r);
    __syncthreads();
  }
}

// ============================ SYTD2 (lower, unblocked; LDS A for small) ============================
template<int NT>
__device__ void sytd2_dev(int n, double* A, double* sd, double* se, double* stau,
                          double* szv, double* red, double* dcom){
  const int tid = threadIdx.x;
  for (int i = 0; i < n-1; i++) {
    double part = 0.0;
#pragma unroll 4
    for (int r = i+2+tid; r < n; r += NT) { double v = A[(size_t)i*n + r]; part += v*v; }
    red[tid] = part; __syncthreads();
    for (int s = NT/2; s > 0; s >>= 1) { if (tid < s) red[tid] += red[tid+s]; __syncthreads(); }
    if (tid == 0) {
      double xnorm = sqrt(red[0]);
      double alpha = A[(size_t)i*n + i + 1];
      double taui, scalf = 0.0;
      if (xnorm == 0.0) { taui = 0.0; se[i] = alpha; }
      else {
        double beta = -d_sign(dlapy2(alpha, xnorm), alpha);
        taui = (beta - alpha)/beta;
        scalf = 1.0/(alpha - beta);
        se[i] = beta;
      }
      stau[i] = taui; dcom[0] = taui; dcom[1] = scalf;
    }
    __syncthreads();
    double taui = dcom[0];
    if (taui != 0.0) {
      double scalf = dcom[1];
      for (int r = i+2+tid; r < n; r += NT) A[(size_t)i*n + r] *= scalf;
      __syncthreads();
      if (tid == 0) A[(size_t)i*n + i + 1] = 1.0;
      __syncthreads();
      for (int r = i+1+tid; r < n; r += NT) {
        double acc = 0.0;
#pragma unroll 4
        for (int c = i+1; c <= r; c++) acc += A[(size_t)c*n + r] * A[(size_t)i*n + c];
#pragma unroll 4
        for (int c = r+1; c < n; c++)  acc += A[(size_t)r*n + c] * A[(size_t)i*n + c];
        szv[r] = taui * acc;
      }
      __syncthreads();
      double p2 = 0.0;
#pragma unroll 4
      for (int r = i+1+tid; r < n; r += NT) p2 += szv[r] * A[(size_t)i*n + r];
      red[tid] = p2; __syncthreads();
      for (int s = NT/2; s > 0; s >>= 1) { if (tid < s) red[tid] += red[tid+s]; __syncthreads(); }
      double alpha2 = -0.5*taui*red[0];
      __syncthreads();
      for (int r = i+1+tid; r < n; r += NT) szv[r] += alpha2 * A[(size_t)i*n + r];
      __syncthreads();
      for (int c = i+1+tid; c < n; c += NT) {
        double vc = A[(size_t)i*n + c], wc = szv[c];
#pragma unroll 4
        for (int r = c; r < n; r++)
          A[(size_t)c*n + r] -= A[(size_t)i*n + r]*wc + szv[r]*vc;
      }
      __syncthreads();
      if (tid == 0) A[(size_t)i*n + i + 1] = se[i];
    }
    __syncthreads();
    if (tid == 0) sd[i] = A[(size_t)i*n + i];
    __syncthreads();
  }
  if (tid == 0) sd[n-1] = A[(size_t)(n-1)*n + (n-1)];
  __syncthreads();
}

// ============================ block reduce (shfl + one LDS pass) ============================
template<int NT>
__device__ __forceinline__ double block_sum(double v, double* red){
  for (int off = 32; off > 0; off >>= 1) v += __shfl_down(v, off);
  const int wid = threadIdx.x >> 6, lane = threadIdx.x & 63;
  __syncthreads();
  if (lane == 0) red[wid] = v;
  __syncthreads();
  if (threadIdx.x == 0) {
    double s = 0.0;
    for (int w = 0; w < NT/64; w++) s += red[w];
    red[0] = s;
  }
  __syncthreads();
  return red[0];
}

// ============================ SYTD2 for big n (full-symmetric A, coalesced) ============================
// Requires A to be a bitwise-symmetric full matrix on entry (k_g2p guarantees this).
template<int NT>
__device__ void sytd2_big(int n, double* A, double* sd, double* se, double* stau,
                          double* vv, double* ww, double* red, double* dcom){
  const int tid = threadIdx.x;
  for (int i = 0; i < n-1; i++) {
    const int i1 = i+1;
    double part = 0.0;
#pragma unroll 4
    for (int r = i+2+tid; r < n; r += NT) { double v = A[(size_t)i*n + r]; part += v*v; }
    double nrm2 = block_sum<NT>(part, red);
    if (tid == 0) {
      double xnorm = sqrt(nrm2);
      double alpha = A[(size_t)i*n + i + 1];
      double taui, scalf = 0.0;
      if (xnorm == 0.0) { taui = 0.0; se[i] = alpha; }
      else {
        double beta = -d_sign(dlapy2(alpha, xnorm), alpha);
        taui = (beta - alpha)/beta;
        scalf = 1.0/(alpha - beta);
        se[i] = beta;
      }
      stau[i] = taui; dcom[0] = taui; dcom[1] = scalf;
    }
    __syncthreads();
    double taui = dcom[0];
    if (taui != 0.0) {
      double scalf = dcom[1];
      for (int r = i+2+tid; r < n; r += NT) {
        double v = A[(size_t)i*n + r] * scalf;
        A[(size_t)i*n + r] = v;
        vv[r] = v;
      }
      if (tid == 0) vv[i1] = 1.0;
      __syncthreads();
      // w = taui * A_full(i1:,i1:) * v — coalesced in rows, 8-batched loads, ORDERED accumulation
      for (int r = i1 + tid; r < n; r += NT) {
        double acc = 0.0;
        int c = i1;
        int rem = (n - i1) & 7;
        for (; c < i1 + rem; c++) acc += A[(size_t)c*n + r] * vv[c];
        for (; c < n; c += 8) {
          double x0 = A[(size_t)(c+0)*n + r], x1 = A[(size_t)(c+1)*n + r];
          double x2 = A[(size_t)(c+2)*n + r], x3 = A[(size_t)(c+3)*n + r];
          double x4 = A[(size_t)(c+4)*n + r], x5 = A[(size_t)(c+5)*n + r];
          double x6 = A[(size_t)(c+6)*n + r], x7 = A[(size_t)(c+7)*n + r];
          double v0 = vv[c+0], v1 = vv[c+1], v2 = vv[c+2], v3 = vv[c+3];
          double v4 = vv[c+4], v5 = vv[c+5], v6 = vv[c+6], v7 = vv[c+7];
          acc += x0*v0; acc += x1*v1; acc += x2*v2; acc += x3*v3;
          acc += x4*v4; acc += x5*v5; acc += x6*v6; acc += x7*v7;
        }
        ww[r] = taui * acc;
      }
      __syncthreads();
      double p2 = 0.0;
#pragma unroll 4
      for (int r = i1+tid; r < n; r += NT) p2 += ww[r] * vv[r];
      double dotvw = block_sum<NT>(p2, red);
      double alpha2 = -0.5*taui*dotvw;
      for (int r = i1+tid; r < n; r += NT) ww[r] += alpha2 * vv[r];
      __syncthreads();
      // rank-2 full update, 2D-flattened over (c,r)
      {
        const int m = n - i1;
        const long tot = (long)m*m;
#pragma unroll 4
        for (long x = tid; x < tot; x += NT) {
          int c = i1 + (int)(x / m);
          int r = i1 + (int)(x % m);
          A[(size_t)c*n + r] -= vv[r]*ww[c] + ww[r]*vv[c];
        }
      }
      __syncthreads();
    }
    if (tid == 0) sd[i] = A[(size_t)i*n + i];
    __syncthreads();
  }
  if (tid == 0) sd[n-1] = A[(size_t)(n-1)*n + (n-1)];
  __syncthreads();
}

// ============================ STEDC (divide & conquer) ============================
template<int NT>
__device__ void stedc_dev(int n, double* Z, double* gwrk,
                          double* sd, double* se, double* sdl, double* sw,
                          double* szv, double* ss2, double* dcom,
                          int* indx, int* indxc, int* indxp, int* coltyp,
                          int* indxq, int* iw, int* icom, int* icom2, Cmd* scmd){
  const int tid = threadIdx.x;
  double* q2   = gwrk;
  double* sbuf = gwrk + (size_t)n*n;
  double* qtmp = gwrk + 2*(size_t)n*n;
  double* dtmp = qtmp + (size_t)n*n;
  Cmd* cbuf = (Cmd*)(dtmp + n + 16);

  if (n <= SMLSIZ) {
    dev_steqr<NT>(n, sd, se, Z, n, cbuf, icom, scmd);
    return;
  }
  int startb = 0, nblk = 0;
  while (startb < n) {
    int finish = startb;
    while (finish < n-1) {
      double tiny = D_EPS*sqrt(fabs(sd[finish]))*sqrt(fabs(sd[finish+1]));
      if (fabs(se[finish]) > tiny) finish++; else break;
    }
    int msz = finish - startb + 1;
    nblk++;
    if (msz == 1) { startb = finish+1; continue; }
    if (msz <= SMLSIZ) {
      dev_steqr<NT>(msz, sd+startb, se+startb, Z + (size_t)startb*n + startb, n, cbuf, icom, scmd);
      startb = finish+1; continue;
    }
    if (tid == 0) {
      double onrm = 0.0;
      for (int i = startb; i <= finish; i++) onrm = fmax(onrm, fabs(sd[i]));
      for (int i = startb; i <  finish; i++) onrm = fmax(onrm, fabs(se[i]));
      if (onrm == 0.0) onrm = 1.0;
      dcom[7] = onrm;
      double inv = 1.0/onrm;
      for (int i = startb; i <= finish; i++) sd[i] *= inv;
      for (int i = startb; i <  finish; i++) se[i] *= inv;
    }
    __syncthreads();
    // LAED0 split
    if (tid == 0) {
      iw[0] = msz; int sp0 = 1;
      while (iw[sp0-1] > SMLSIZ) {
        for (int j = sp0-1; j >= 0; j--) { iw[2*j+1] = (iw[j]+1)/2; iw[2*j] = iw[j]/2; }
        sp0 *= 2;
      }
      for (int j = 1; j < sp0; j++) iw[j] += iw[j-1];
      icom[8] = sp0;
      for (int i = 0; i < sp0-1; i++) {
        int bb = startb + iw[i] - 1;
        sd[bb]   -= fabs(se[bb]);
        sd[bb+1] -= fabs(se[bb]);
      }
    }
    __syncthreads();
    int sp = icom[8];
    // ---- parallel leaf STEQR: one leaf per wave (scan on lane 0, replay on lanes) ----
    {
      const int wid = tid >> 6, lane = tid & 63;
      const int nwaves = NT/64;
      for (int li = wid; li < sp; li += nwaves) {
        if (lane == 0) {
          int submat = (li == 0) ? 0 : iw[li-1];
          int matsiz = iw[li] - submat;
          icom2[li] = (matsiz > 1)
            ? steqr_scan(matsiz, sd+startb+submat, se+startb+submat, cbuf + (size_t)li*CMDMAX, CMDMAX)
            : 0;
        }
      }
      __syncthreads();
      for (int li = wid; li < sp; li += nwaves) {
        int submat = (li == 0) ? 0 : iw[li-1];
        int matsiz = iw[li] - submat;
        int nc = icom2[li];
        double* zb = Z + (size_t)(startb+submat)*n + (startb+submat);
        Cmd* cb = cbuf + (size_t)li*CMDMAX;
        if (lane < matsiz) {
#pragma unroll 2
          for (int q = 0; q < nc; q++) apply_cmd(cb[q], zb, n, lane);
        }
      }
      __syncthreads();
      for (int x = tid; x < msz; x += NT) {
        int sub = 0;
        for (int t = 0; t < sp; t++) { if (x < iw[t]) { sub = (t == 0) ? 0 : iw[t-1]; break; } }
        indxq[startb + x] = x - sub;
      }
      __syncthreads();
    }
    while (sp > 1) {
      for (int i2 = 0; i2 <= sp-2; i2 += 2) {
        int submat, matsiz, msd2;
        if (i2 == 0) { submat = 0; matsiz = iw[1]; msd2 = iw[0]; }
        else { submat = iw[i2-1]; matsiz = iw[i2+1]-iw[i2-1]; msd2 = matsiz/2; }
        // LAED1
        {
          const int nm = matsiz, n1 = msd2, ldn = n;
          double* dm = sd + startb + submat;
          double* qb = Z + (size_t)(startb+submat)*n + (startb+submat);
          int* ixq = indxq + startb + submat;
          double rho_in = se[startb+submat+msd2-1];
          for (int i = tid; i < n1; i += NT)      szv[i] = qb[(size_t)i*ldn + (n1-1)];
          for (int i = n1+tid; i < nm; i += NT)   szv[i] = qb[(size_t)i*ldn + n1];
          __syncthreads();
          // LAED2 scan (thread 0) — Givens rotations RECORDED into cbuf, replayed in parallel
          if (tid == 0) {
            int nrot = 0;
            const int n2_ = nm - n1;
            double rho = rho_in;
            if (rho < 0.0) for (int i = n1; i < nm; i++) szv[i] = -szv[i];
            double tsc = 1.0/sqrt(2.0);
            for (int i = 0; i < nm; i++) szv[i] *= tsc;
            rho = fabs(2.0*rho);
            dcom[0] = rho;
            for (int i = n1; i < nm; i++) ixq[i] += n1;
            for (int i = 0; i < nm; i++) sdl[i] = dm[ixq[i]];
            dlamrg(n1, n2_, sdl, 1, 1, indxc);
            for (int i = 0; i < nm; i++) indx[i] = ixq[indxc[i]];
            int imax = 0, jmax = 0;
            for (int i = 1; i < nm; i++) {
              if (fabs(szv[i]) > fabs(szv[imax])) imax = i;
              if (fabs(dm[i])  > fabs(dm[jmax]))  jmax = i;
            }
            double tol = 8.0*D_EPS*fmax(fabs(dm[jmax]), fabs(szv[imax]));
            if (rho*fabs(szv[imax]) <= tol) {
              icom[1] = 0;
              for (int j = 0; j < nm; j++) sdl[j] = dm[indx[j]];
            } else {
              for (int i = 0; i < n1; i++) coltyp[i] = 0;
              for (int i = n1; i < nm; i++) coltyp[i] = 2;
              int k = 0, k2 = nm;
              int pj = 0, jj = 0;
              bool haveP = false;
              for (jj = 0; jj < nm; jj++) {
                int nj = indx[jj];
                if (rho*fabs(szv[nj]) <= tol) { k2--; coltyp[nj] = 3; indxp[k2] = nj; }
                else { pj = nj; haveP = true; jj++; break; }
              }
              if (haveP) {
                while (1) {
                  if (jj > nm-1) break;
                  int nj = indx[jj];
                  if (rho*fabs(szv[nj]) <= tol) { k2--; coltyp[nj] = 3; indxp[k2] = nj; }
                  else {
                    double s_ = szv[pj], c_ = szv[nj];
                    double tau = dlapy2(c_, s_);
                    double tdf = dm[nj] - dm[pj];
                    c_ = c_/tau; s_ = -s_/tau;
                    if (fabs(tdf*c_*s_) <= tol) {
                      szv[nj] = tau; szv[pj] = 0.0;
                      if (coltyp[nj] != coltyp[pj]) coltyp[nj] = 1;
                      coltyp[pj] = 3;
                      if (nrot < CMDMAX) { cbuf[nrot].c = c_; cbuf[nrot].s = s_; cbuf[nrot].a = pj; cbuf[nrot].b = nj; }
                      nrot++;
                      double t2 = dm[pj]*c_*c_ + dm[nj]*s_*s_;
                      dm[nj] = dm[pj]*s_*s_ + dm[nj]*c_*c_;
                      dm[pj] = t2;
                      k2--;
                      int i1 = 1;
                      while (1) {
                        if (k2 + i1 <= nm-1) {
                          if (dm[pj] < dm[indxp[k2+i1]]) {
                            indxp[k2+i1-1] = indxp[k2+i1];
                            indxp[k2+i1] = pj;
                            i1++;
                          } else { indxp[k2+i1-1] = pj; break; }
                        } else { indxp[k2+i1-1] = pj; break; }
                      }
                      pj = nj;
                    } else {
                      k++; sdl[k-1] = dm[pj]; sw[k-1] = szv[pj]; indxp[k-1] = pj; pj = nj;
                    }
                  }
                  jj++;
                }
                k++; sdl[k-1] = dm[pj]; sw[k-1] = szv[pj]; indxp[k-1] = pj;
              }
              int ct[4] = {0,0,0,0};
              for (int j = 0; j < nm; j++) ct[coltyp[j]]++;
              int psm[4];
              psm[0] = 0; psm[1] = ct[0]; psm[2] = ct[0]+ct[1]; psm[3] = ct[0]+ct[1]+ct[2];
              for (int j = 0; j < nm; j++) {
                int js = indxp[j], c4 = coltyp[js];
                indx[psm[c4]] = js; indxc[psm[c4]] = j; psm[c4]++;
              }
              icom[1] = k; icom[2] = ct[0]; icom[3] = ct[1]; icom[4] = ct[2]; icom[5] = ct[3];
            }
            icom[6] = (nrot <= CMDMAX) ? nrot : CMDMAX;
          }
          __syncthreads();
          // ---- parallel replay of deflation Givens rotations (row-ordered) ----
          {
            int nrot = icom[6];
            for (int base = 0; base < nrot; base += SCHUNK) {
              int cnt = nrot - base; if (cnt > SCHUNK) cnt = SCHUNK;
              for (int q = tid; q < cnt; q += NT) scmd[q] = cbuf[base+q];
              __syncthreads();
              for (int r = tid; r < nm; r += NT) {
#pragma unroll 2
                for (int q = 0; q < cnt; q++) {
                  Cmd cm = scmd[q];
                  double x = qb[(size_t)cm.a*ldn + r], y = qb[(size_t)cm.b*ldn + r];
                  qb[(size_t)cm.a*ldn + r] = cm.c*x + cm.s*y;
                  qb[(size_t)cm.b*ldn + r] = cm.c*y - cm.s*x;
                }
              }
              __syncthreads();
            }
          }
          int K = icom[1];
          if (K == 0) {
            for (int fl = tid; fl < nm*nm; fl += NT) {
              int jj2 = fl/nm, r = fl%nm;
              q2[(size_t)jj2*nm + r] = qb[(size_t)indx[jj2]*ldn + r];
            }
            __syncthreads();
            for (int fl = tid; fl < nm*nm; fl += NT) {
              int jj2 = fl/nm, r = fl%nm;
              qb[(size_t)jj2*ldn + r] = q2[(size_t)jj2*nm + r];
            }
            for (int i = tid; i < nm; i += NT) dm[i] = sdl[i];
            for (int i = tid; i < nm; i += NT) ixq[i] = i;
            __syncthreads();
          } else {
            int ct0 = icom[2], ct1 = icom[3], ct2 = icom[4];
            int n2c = nm - n1;
            int base2 = (ct0+ct1)*n1;
            int base4 = base2 + (ct1+ct2)*n2c;
            for (int i = tid; i < nm; i += NT) {
              int js = indx[i];
              const double* col = qb + (size_t)js*ldn;
              if (i < ct0) {
                double* dst = q2 + (size_t)i*n1;
#pragma unroll 4
                for (int r = 0; r < n1; r++) dst[r] = col[r];
              } else if (i < ct0+ct1) {
                double* d1 = q2 + (size_t)i*n1;
#pragma unroll 4
                for (int r = 0; r < n1; r++) d1[r] = col[r];
                double* d2 = q2 + base2 + (size_t)(i-ct0)*n2c;
#pragma unroll 4
                for (int r = 0; r < n2c; r++) d2[r] = col[n1+r];
              } else if (i < K) {
                double* d2 = q2 + base2 + (size_t)(i-ct0)*n2c;
#pragma unroll 4
                for (int r = 0; r < n2c; r++) d2[r] = col[n1+r];
              } else {
                double* d4 = q2 + base4 + (size_t)(i-K)*nm;
#pragma unroll 4
                for (int r = 0; r < nm; r++) d4[r] = col[r];
              }
              szv[i] = dm[js];
            }
            __syncthreads();
            for (int fl = tid; fl < (nm-K)*nm; fl += NT) {
              int jj2 = fl/nm, r = fl%nm;
              qb[(size_t)(K+jj2)*ldn + r] = q2[base4 + (size_t)jj2*nm + r];
            }
            for (int i = K+tid; i < nm; i += NT) dm[i] = szv[i];
            __syncthreads();
            // LAED3
            double rho = dcom[0];
            for (int j = tid; j < K; j += NT) {
              double lam;
              my_laed4(K, j, sdl, sw, rho, qb + (size_t)j*ldn, &lam);
              dm[j] = lam;
            }
            __syncthreads();
            if (K == 2) {
              if (tid == 0) {
                for (int j = 0; j < 2; j++) {
                  double a0 = qb[(size_t)j*ldn + 0], a1 = qb[(size_t)j*ldn + 1];
                  qb[(size_t)j*ldn + 0] = (indxc[0] == 0) ? a0 : a1;
                  qb[(size_t)j*ldn + 1] = (indxc[1] == 0) ? a0 : a1;
                }
              }
              __syncthreads();
            } else if (K >= 3) {
              for (int i = tid; i < K; i += NT) szv[i] = sw[i];
              __syncthreads();
              for (int i = tid; i < K; i += NT) {
                double prod = qb[(size_t)i*ldn + i];
#pragma unroll 4
                for (int j = 0; j < K; j++) {
                  if (j == i) continue;
                  prod *= qb[(size_t)j*ldn + i] / (sdl[i]-sdl[j]);
                }
                sw[i] = d_sign(sqrt(fmax(-prod, 0.0)), szv[i]);
              }
              __syncthreads();
              for (int j = tid; j < K; j += NT) {
                double nrm = 0.0;
#pragma unroll 4
                for (int i = 0; i < K; i++) {
                  double v = sw[i]/qb[(size_t)j*ldn + i];
                  sbuf[(size_t)j*K + i] = v;
                  nrm += v*v;
                }
                ss2[j] = sqrt(nrm);
              }
              __syncthreads();
              for (int fl = tid; fl < K*K; fl += NT) {
                int jj2 = fl/K, i = fl%K;
                qb[(size_t)jj2*ldn + i] = sbuf[(size_t)jj2*K + indxc[i]] / ss2[jj2];
              }
              __syncthreads();
            }
            // assembly
            int n12 = ct0+ct1, n23 = ct1+ct2;
            for (int fl = tid; fl < n23*K; fl += NT) {
              int jj2 = fl/n23, i = fl%n23;
              sbuf[(size_t)jj2*n23 + i] = qb[(size_t)jj2*ldn + ct0 + i];
            }
            __syncthreads();
            // GEMM 1: qb[jj2, n1+r] = sum_l q2[base2 + l*n2c + r] * sbuf[jj2*n23 + l]
            // 8-batched loads, ORDERED accumulation (bitwise-identical to serial loop)
            for (int fl = tid; fl < n2c*K; fl += NT) {
              int jj2 = fl/n2c, r = fl%n2c;
              const double* srow = sbuf + (size_t)jj2*n23;
              double acc = 0.0;
              int l = 0;
              int rem = n23 & 7;
              for (; l < rem; l++) acc += q2[base2 + (size_t)l*n2c + r] * srow[l];
              for (; l < n23; l += 8) {
                double x0 = q2[base2 + (size_t)(l+0)*n2c + r];
                double x1 = q2[base2 + (size_t)(l+1)*n2c + r];
                double x2 = q2[base2 + (size_t)(l+2)*n2c + r];
                double x3 = q2[base2 + (size_t)(l+3)*n2c + r];
                double x4 = q2[base2 + (size_t)(l+4)*n2c + r];
                double x5 = q2[base2 + (size_t)(l+5)*n2c + r];
                double x6 = q2[base2 + (size_t)(l+6)*n2c + r];
                double x7 = q2[base2 + (size_t)(l+7)*n2c + r];
                double y0 = srow[l+0], y1 = srow[l+1], y2 = srow[l+2], y3 = srow[l+3];
                double y4 = srow[l+4], y5 = srow[l+5], y6 = srow[l+6], y7 = srow[l+7];
                acc += x0*y0; acc += x1*y1; acc += x2*y2; acc += x3*y3;
                acc += x4*y4; acc += x5*y5; acc += x6*y6; acc += x7*y7;
              }
              qb[(size_t)jj2*ldn + n1 + r] = acc;
            }
            __syncthreads();
            for (int fl = tid; fl < n12*K; fl += NT) {
              int jj2 = fl/n12, i = fl%n12;
              sbuf[(size_t)jj2*n12 + i] = qb[(size_t)jj2*ldn + i];
            }
            __syncthreads();
            // GEMM 2: qb[jj2, r] = sum_l q2[l*n1 + r] * sbuf[jj2*n12 + l]  (8-batched, ordered)
            for (int fl = tid; fl < n1*K; fl += NT) {
              int jj2 = fl/n1, r = fl%n1;
              const double* srow = sbuf + (size_t)jj2*n12;
              double acc = 0.0;
              int l = 0;
              int rem = n12 & 7;
              for (; l < rem; l++) acc += q2[(size_t)l*n1 + r] * srow[l];
              for (; l < n12; l += 8) {
                double x0 = q2[(size_t)(l+0)*n1 + r];
                double x1 = q2[(size_t)(l+1)*n1 + r];
                double x2 = q2[(size_t)(l+2)*n1 + r];
                double x3 = q2[(size_t)(l+3)*n1 + r];
                double x4 = q2[(size_t)(l+4)*n1 + r];
                double x5 = q2[(size_t)(l+5)*n1 + r];
                double x6 = q2[(size_t)(l+6)*n1 + r];
                double x7 = q2[(size_t)(l+7)*n1 + r];
                double y0 = srow[l+0], y1 = srow[l+1], y2 = srow[l+2], y3 = srow[l+3];
                double y4 = srow[l+4], y5 = srow[l+5], y6 = srow[l+6], y7 = srow[l+7];
                acc += x0*y0; acc += x1*y1; acc += x2*y2; acc += x3*y3;
                acc += x4*y4; acc += x5*y5; acc += x6*y6; acc += x7*y7;
              }
              qb[(size_t)jj2*ldn + r] = acc;
            }
            __syncthreads();
            if (tid == 0) dlamrg(K, nm-K, dm, 1, -1, ixq);
            __syncthreads();
          }
        }
        if (tid == 0) iw[i2/2] = iw[i2+1];
        __syncthreads();
      }
      sp /= 2;
    }
    // final reorder by indxq
    {
      int msz2 = finish - startb + 1;
      for (int i = tid; i < msz2; i += NT) dtmp[i] = sd[startb + indxq[startb+i]];
      for (int fl = tid; fl < msz2*msz2; fl += NT) {
        int i = fl/msz2, r = fl%msz2;
        qtmp[(size_t)i*msz2 + r] = Z[(size_t)(startb + indxq[startb+i])*n + startb + r];
      }
      __syncthreads();
      for (int i = tid; i < msz2; i += NT) sd[startb+i] = dtmp[i];
      for (int fl = tid; fl < msz2*msz2; fl += NT) {
        int i = fl/msz2, r = fl%msz2;
        Z[(size_t)(startb+i)*n + startb + r] = qtmp[(size_t)i*msz2 + r];
      }
      __syncthreads();
      if (tid == 0) {
        double onrm = dcom[7];
        for (int i = startb; i <= finish; i++) sd[i] *= onrm;
      }
      __syncthreads();
    }
    startb = finish + 1;
  }
  if (nblk > 1) {
    for (int ii = 1; ii <= n-1; ii++) {
      if (tid == 0) {
        int i = ii-1, kk = i; double p = sd[i];
        for (int j = ii; j <= n-1; j++) if (sd[j] < p) { kk = j; p = sd[j]; }
        icom[7] = kk;
        if (kk != i) { sd[kk] = sd[i]; sd[i] = p; }
      }
      __syncthreads();
      int kk = icom[7], i = ii-1;
      if (kk != i) {
        for (int r = tid; r < n; r += NT) {
          double t = Z[(size_t)i*n + r];
          Z[(size_t)i*n + r] = Z[(size_t)kk*n + r];
          Z[(size_t)kk*n + r] = t;
        }
      }
      __syncthreads();
    }
  }
}

// ============================ eigh kernels ============================
// Small: n <= 96, A and Z resident in dynamic LDS. Full pipeline in one launch.
template<int NT, int MAXN>
__global__ __launch_bounds__(NT) void k_eigh_small(int n, const double* __restrict__ Ain,
                                                   double* __restrict__ Zout,
                                                   double* __restrict__ Dout,
                                                   double* gwrk){
  __shared__ double sd[MAXN], se[MAXN], stau[MAXN], sdl[MAXN], sw[MAXN], szv[MAXN], ss2[MAXN];
  __shared__ double red[NT], dcom[8];
  __shared__ int indx[MAXN], indxc[MAXN], indxp[MAXN], coltyp[MAXN], indxq[MAXN];
  __shared__ int iw[40], icom[16], icom2[16];
  __shared__ Cmd scmd[SCHUNK];
  extern __shared__ double dyn[];
  double* A = dyn;
  double* Z = dyn + n*n;
  const int tid = threadIdx.x;

  for (int x = tid; x < n*n; x += NT) A[x] = Ain[x];
  __syncthreads();

  sytd2_dev<NT>(n, A, sd, se, stau, szv, red, dcom);

  for (int x = tid; x < n*n; x += NT) Z[x] = ((x % (n+1)) == 0) ? 1.0 : 0.0;
  __syncthreads();

  stedc_dev<NT>(n, Z, gwrk, sd, se, sdl, sw, szv, ss2, dcom,
                indx, indxc, indxp, coltyp, indxq, iw, icom, icom2, scmd);

  // ORMTR: Z := Q * Z (column-parallel, all LDS-resident)
  __syncthreads();
  for (int j = tid; j < n; j += NT) {
    for (int ii = n-2; ii >= 0; ii--) {
      double tau_i = stau[ii];
      if (tau_i == 0.0) continue;
      double w = Z[(size_t)j*n + ii + 1];
#pragma unroll 4
      for (int r = ii+2; r < n; r++) w += A[(size_t)ii*n + r] * Z[(size_t)j*n + r];
      w *= tau_i;
      Z[(size_t)j*n + ii + 1] -= w;
#pragma unroll 4
      for (int r = ii+2; r < n; r++) Z[(size_t)j*n + r] -= w * A[(size_t)ii*n + r];
    }
  }
  __syncthreads();
  for (int x = tid; x < n*n; x += NT) Zout[x] = Z[x];
  for (int i = tid; i < n; i += NT) Dout[i] = sd[i];
}

// ---------- Big n = 384: phase-split kernels for profiling attribution ----------
template<int NT>
__global__ __launch_bounds__(NT) void k_sytd2_big(int n, double* A,
                                                  double* gsd, double* gse, double* gtau){
  __shared__ double sd[384], se[384], stau[384], vv[384], ww[384];
  __shared__ double red[16], dcom[8];
  const int tid = threadIdx.x;
  sytd2_big<NT>(n, A, sd, se, stau, vv, ww, red, dcom);
  for (int i = tid; i < n; i += NT) {
    gsd[i] = sd[i];
    gtau[i] = stau[i];
    if (i < n-1) gse[i] = se[i];
  }
}

template<int NT>
__global__ __launch_bounds__(NT) void k_stedc_big(int n, double* Z, double* Dout,
                                                  double* gwrk,
                                                  const double* gsd, const double* gse){
  __shared__ double sd[384], se[384], sdl[384], sw[384], szv[384], ss2[384];
  __shared__ double dcom[8];
  __shared__ int indx[384], indxc[384], indxp[384], coltyp[384], indxq[384];
  __shared__ int iw[40], icom[16], icom2[16];
  __shared__ Cmd scmd[SCHUNK];
  const int tid = threadIdx.x;

  for (int i = tid; i < n; i += NT) {
    sd[i] = gsd[i];
    if (i < n-1) se[i] = gse[i];
  }
  for (size_t x = tid; x < (size_t)n*n; x += NT) Z[x] = ((x % (size_t)(n+1)) == 0) ? 1.0 : 0.0;
  __syncthreads();

  stedc_dev<NT>(n, Z, gwrk, sd, se, sdl, sw, szv, ss2, dcom,
                indx, indxc, indxp, coltyp, indxq, iw, icom, icom2, scmd);

  for (int i = tid; i < n; i += NT) Dout[i] = sd[i];
}

// Multi-block ORMTR for big n: each block owns OB_COLS columns (from col0) of Z in LDS.
#define OB_COLS 8
__global__ __launch_bounds__(256) void k_ormtr_big(int n, const double* __restrict__ A,
                                                   double* __restrict__ Z,
                                                   const double* __restrict__ tau,
                                                   int col0base){
  __shared__ double zc[OB_COLS][384];
  __shared__ double vsh[384];
  int col0 = col0base + blockIdx.x * OB_COLS;
  int tid = threadIdx.x;
  int c = tid >> 5;       // column slot 0..7
  int l = tid & 31;       // lane within column group
  for (int x = tid; x < OB_COLS*n; x += 256) {
    int cc = x / n, r = x % n;
    if (col0+cc < n) zc[cc][r] = Z[(size_t)(col0+cc)*n + r];
  }
  __syncthreads();
  for (int ii = n-2; ii >= 0; ii--) {
    double ti = tau[ii];
    if (ti != 0.0) {
      for (int r = ii+2+tid; r < n; r += 256) vsh[r] = A[(size_t)ii*n + r];
      __syncthreads();
      double p = (l == 0) ? zc[c][ii+1] : 0.0;
#pragma unroll 4
      for (int r = ii+2+l; r < n; r += 32) p += vsh[r]*zc[c][r];
      for (int off = 16; off > 0; off >>= 1) p += __shfl_down(p, off, 32);
      double w = __shfl(p, 0, 32) * ti;
      if (l == 0) zc[c][ii+1] -= w;
#pragma unroll 4
      for (int r = ii+2+l; r < n; r += 32) zc[c][r] -= w*vsh[r];
      __syncthreads();
    }
  }
  for (int x = tid; x < OB_COLS*n; x += 256) {
    int cc = x / n, r = x % n;
    if (col0+cc < n) Z[(size_t)(col0+cc)*n + r] = zc[cc][r];
  }
}

// ============================ data kernels ============================
__global__ __launch_bounds__(TPB) void k_conv(const float* __restrict__ st,
                                              const float* __restrict__ cw,
                                              const float* __restrict__ cb,
                                              float* __restrict__ sv){
  int idx = blockIdx.x*TPB + threadIdx.x;
  if (idx >= 28311552) return;
  int w = idx % 24; int t = idx/24;
  int h = t % 384; t /= 384;
  int d = t % 96; int o = t/96;
  float acc = cb[o];
  for (int i = 0; i < 4; i++)
    for (int kh = 0; kh < 3; kh++)
      acc += st[(((size_t)i*96+d)*386 + h+kh)*24 + w] * cw[(o*4+i)*3 + kh];
  sv[idx] = fmaxf(acc, 0.0f);
}

// padded-stride (25) LDS slabs: stride 25 is coprime with 32 banks -> conflict-free
__global__ __launch_bounds__(TPB) void k_g0p(const float* __restrict__ sv, double* parts){
  __shared__ float slab[32*25];
  int b = blockIdx.x; // 288
  double acc[4]; int c1s[4], c2s[4];
#pragma unroll
  for (int k = 0; k < 4; k++) { int e = threadIdx.x + k*TPB; acc[k] = 0.0; c1s[k] = e/32; c2s[k] = e%32; }
  for (int q = 0; q < 128; q++) {
    int s = b*128 + q; int d = s/384, p = s%384;
    for (int l = threadIdx.x; l < 768; l += TPB) {
      int cc = l/24, w = l-cc*24;
      slab[cc*25+w] = sv[(((size_t)cc*96+d)*384+p)*24 + w];
    }
    __syncthreads();
#pragma unroll
    for (int k = 0; k < 4; k++) {
      double sacc = 0.0;
      const float* r1 = slab + c1s[k]*25;
      const float* r2 = slab + c2s[k]*25;
      for (int w = 0; w < 24; w++) sacc += (double)r1[w]*(double)r2[w];
      acc[k] += sacc;
    }
    __syncthreads();
  }
  for (int k = 0; k < 4; k++) parts[(size_t)b*1024 + threadIdx.x + k*TPB] = acc[k];
}
__global__ __launch_bounds__(TPB) void k_g1p(const float* __restrict__ sv, double* parts){
  __shared__ float slab[96*25];
  int c = blockIdx.x; // 32
  double acc[36]; int d1s[36], d2s[36];
#pragma unroll
  for (int k = 0; k < 36; k++) { int e = threadIdx.x + k*TPB; acc[k] = 0.0; d1s[k] = e/96; d2s[k] = e%96; }
  for (int p = 0; p < 384; p++) {
    for (int l = threadIdx.x; l < 2304; l += TPB) {
      int d = l/24, w = l-d*24;
      slab[d*25+w] = sv[(((size_t)c*96+d)*384+p)*24 + w];
    }
    __syncthreads();
#pragma unroll
    for (int k = 0; k < 36; k++) {
      double sacc = 0.0;
      const float* r1 = slab + d1s[k]*25;
      const float* r2 = slab + d2s[k]*25;
      for (int w = 0; w < 24; w++) sacc += (double)r1[w]*(double)r2[w];
      acc[k] += sacc;
    }
    __syncthreads();
  }
  for (int k = 0; k < 36; k++) parts[(size_t)c*9216 + threadIdx.x + k*TPB] = acc[k];
}
#define G2_NKG 6
__global__ __launch_bounds__(TPB) void k_g2p(const float* __restrict__ sv, double* parts){
  __shared__ float aS[64*25], bS[64*25];
  int blk = blockIdx.x; // 6*36
  int kg = blk/36, t2 = blk%36, tI = t2/6, tJ = t2%6;
  int tr = (threadIdx.x/16)*4, tc = (threadIdx.x%16)*4;
  double acc[4][4];
#pragma unroll
  for (int i = 0; i < 4; i++)
#pragma unroll
    for (int j = 0; j < 4; j++) acc[i][j] = 0.0;
  for (int ss = 0; ss < 512; ss++) {
    int s = kg*512 + ss;
    size_t base = (size_t)s*9216;
    for (int l = threadIdx.x; l < 1536; l += TPB) {
      int row = l/24, w = l-row*24;
      aS[row*25+w] = sv[base + (size_t)tI*1536 + l];
      bS[row*25+w] = sv[base + (size_t)tJ*1536 + l];
    }
    __syncthreads();
    for (int w = 0; w < 24; w++) {
      double a0 = aS[(tr+0)*25+w], a1 = aS[(tr+1)*25+w], a2 = aS[(tr+2)*25+w], a3 = aS[(tr+3)*25+w];
      double b0 = bS[(tc+0)*25+w], b1 = bS[(tc+1)*25+w], b2 = bS[(tc+2)*25+w], b3 = bS[(tc+3)*25+w];
      acc[0][0]+=a0*b0; acc[0][1]+=a0*b1; acc[0][2]+=a0*b2; acc[0][3]+=a0*b3;
      acc[1][0]+=a1*b0; acc[1][1]+=a1*b1; acc[1][2]+=a1*b2; acc[1][3]+=a1*b3;
      acc[2][0]+=a2*b0; acc[2][1]+=a2*b1; acc[2][2]+=a2*b2; acc[2][3]+=a2*b3;
      acc[3][0]+=a3*b0; acc[3][1]+=a3*b1; acc[3][2]+=a3*b2; acc[3][3]+=a3*b3;
    }
    __syncthreads();
  }
  for (int i = 0; i < 4; i++)
    for (int j = 0; j < 4; j++)
      parts[(size_t)kg*147456 + (size_t)(tI*64+tr+i)*384 + (tJ*64+tc+j)] = acc[i][j];
}
__global__ __launch_bounds__(TPB) void k_g3p(const float* __restrict__ sv, double* parts){
  __shared__ float slab[9216];
  int b = blockIdx.x; // 128
  double acc[3]; int w1s[3], w2s[3];
#pragma unroll
  for (int k = 0; k < 3; k++) { int e = threadIdx.x + k*TPB; acc[k] = 0.0; w1s[k] = e/24; w2s[k] = e%24; }
  for (int q = 0; q < 24; q++) {
    int s = b*24 + q;
    size_t base = (size_t)s*9216;
    for (int l = threadIdx.x; l < 9216; l += TPB) slab[l] = sv[base + l];
    __syncthreads();
#pragma unroll
    for (int k = 0; k < 3; k++) {
      int e = threadIdx.x + k*TPB;
      if (e < 576) {
        double sacc = 0.0;
#pragma unroll 4
        for (int p = 0; p < 384; p++) sacc += (double)slab[p*24+w1s[k]]*(double)slab[p*24+w2s[k]];
        acc[k] += sacc;
      }
    }
    __syncthreads();
  }
  for (int k = 0; k < 3; k++) {
    int e = threadIdx.x + k*TPB;
    if (e < 576) parts[(size_t)b*576 + e] = acc[k];
  }
}
__global__ __launch_bounds__(TPB) void k_reduce(double* out, const double* parts, int np, int len){
  int i = blockIdx.x*TPB + threadIdx.x;
  if (i >= len) return;
  double acc = 0.0;
#pragma unroll 4
  for (int p = 0; p < np; p++) acc += parts[(size_t)p*len + i];
  out[i] = acc;
}

__global__ __launch_bounds__(TPB) void k_c2sv(const float* __restrict__ sv,
                                              const double* __restrict__ U2,
                                              double* __restrict__ out){
  __shared__ float slab[9216];
  __shared__ double u2s[2304];
  for (int l = threadIdx.x; l < 2304; l += TPB) u2s[l] = U2[l];
  size_t base = (size_t)blockIdx.x*9216;
  for (int l = threadIdx.x; l < 9216; l += TPB) slab[l] = sv[base + l];
  __syncthreads();
  int t = threadIdx.x;
  if (t < 144) {
    int j = t/24, w = t%24;
    double acc = 0.0;
#pragma unroll 8
    for (int p = 0; p < 384; p++) acc += (double)slab[p*24+w]*u2s[p*6+j];
    out[(size_t)blockIdx.x*144 + t] = acc;
  }
}
__global__ __launch_bounds__(TPB) void k_c1sv(const float* __restrict__ sv,
                                              const double* __restrict__ U1,
                                              double* __restrict__ out){
  int t = blockIdx.x*TPB + threadIdx.x;
  if (t >= 294912) return;
  int c = t/9216; int rem = t%9216; int p = rem/24; int w = rem%24;
  double a0 = 0.0, a1 = 0.0;
#pragma unroll 4
  for (int d = 0; d < 96; d++) {
    double v = (double)sv[(((size_t)c*96+d)*384+p)*24 + w];
    a0 += v*U1[d*2+0];
    a1 += v*U1[d*2+1];
  }
  out[((size_t)c*2+0)*9216 + p*24 + w] = a0;
  out[((size_t)c*2+1)*9216 + p*24 + w] = a1;
}
__global__ __launch_bounds__(TPB) void k_contract4(const double* __restrict__ in,
                                                   const double* __restrict__ U,
                                                   double* __restrict__ out,
                                                   int s0, int s1, int s2, int s3,
                                                   int ax, int r){
  int os0 = (ax==0)?r:s0, os1 = (ax==1)?r:s1, os2 = (ax==2)?r:s2, os3 = (ax==3)?r:s3;
  long tot = (long)os0*os1*os2*os3;
  long str3 = 1, str2 = s3, str1 = (long)s2*s3, str0 = (long)s1*s2*s3;
  for (long idx = blockIdx.x*(long)TPB + threadIdx.x; idx < tot; idx += (long)gridDim.x*TPB) {
    long t = idx;
    int i3 = (int)(t % os3); t /= os3;
    int i2 = (int)(t % os2); t /= os2;
    int i1 = (int)(t % os1); int i0 = (int)(t/os1);
    int j;
    long base; long st; int sa;
    if (ax == 0)      { j = i0; base = (long)i1*str1 + i2*str2 + i3; st = str0; sa = s0; }
    else if (ax == 1) { j = i1; base = (long)i0*str0 + i2*str2 + i3; st = str1; sa = s1; }
    else if (ax == 2) { j = i2; base = (long)i0*str0 + i1*str1 + i3; st = str2; sa = s2; }
    else              { j = i3; base = (long)i0*str0 + i1*str1 + i2*str2; st = str3; sa = s3; }
    double acc = 0.0;
#pragma unroll 4
    for (int c = 0; c < sa; c++) acc += in[base + (long)c*st] * U[c*r + j];
    out[idx] = acc;
  }
}

__global__ __launch_bounds__(TPB) void k_gram_sw0(const double* __restrict__ y, double* G){
  for (int e = threadIdx.x; e < 576; e += TPB) {
    int c1 = e/24, c2 = e%24;
    double acc = 0.0;
#pragma unroll 4
    for (int i = 0; i < 32; i++) acc += y[i*24+c1]*y[i*24+c2];
    G[e] = acc;
  }
}
__global__ __launch_bounds__(TPB) void k_gram_sw1(const double* __restrict__ y, double* G){
  for (int e = threadIdx.x; e < 9216; e += TPB) {
    int d1 = e/96, d2 = e%96;
    double acc = 0.0;
#pragma unroll 2
    for (int a = 0; a < 8; a++)
#pragma unroll
      for (int ee = 0; ee < 6; ee++)
#pragma unroll
        for (int m = 0; m < 2; m++)
          acc += y[(((size_t)a*96+d1)*6+ee)*2+m]*y[(((size_t)a*96+d2)*6+ee)*2+m];
    G[e] = acc;
  }
}
__global__ __launch_bounds__(TPB) void k_gram_sw2(const double* __restrict__ y, double* G){
  for (int e = threadIdx.x; e < 1024; e += TPB) {
    int q1 = e/32, q2 = e%32;
    double acc = 0.0;
#pragma unroll 4
    for (int p = 0; p < 384; p++)
      acc += y[(size_t)(q1>>1)*768 + p*2 + (q1&1)]*y[(size_t)(q2>>1)*768 + p*2 + (q2&1)];
    G[e] = acc;
  }
}
__global__ __launch_bounds__(TPB) void k_gram_sw3(const double* __restrict__ y, double* G){
  for (int e = threadIdx.x; e < 576; e += TPB) {
    int w1 = e/24, w2 = e%24;
    double acc = 0.0;
#pragma unroll 2
    for (int a = 0; a < 8; a++)
#pragma unroll
      for (int j = 0; j < 2; j++)
#pragma unroll
        for (int ee = 0; ee < 6; ee++)
          acc += y[(((size_t)a*2+j)*6+ee)*24+w1]*y[(((size_t)a*2+j)*6+ee)*24+w2];
    G[e] = acc;
  }
}

__global__ __launch_bounds__(TPB) void k_fact_sq(double* U, const double* Z, int n, int r){
  int t = blockIdx.x*TPB + threadIdx.x;
  if (t >= n*r) return;
  int i = t/r, j = t%r;
  U[t] = Z[(size_t)(n-1-j)*n + i];
}
__global__ __launch_bounds__(TPB) void k_factT0(double* U0, const double* y,
                                                const double* Z, const double* D){
  int t = threadIdx.x;
  if (t >= 256) return;
  int i = t/8, j = t%8;
  int col = 23-j;
  double acc = 0.0;
#pragma unroll 4
  for (int c = 0; c < 24; c++) acc += y[i*24+c]*Z[(size_t)col*24+c];
  U0[t] = acc / sqrt(fmax(D[col], 1e-12));
}
__global__ __launch_bounds__(TPB) void k_factT2(double* U2, const double* y,
                                                const double* Z, const double* D){
  int t = blockIdx.x*TPB + threadIdx.x;
  if (t >= 2304) return;
  int p = t/6, j = t%6;
  int col = 31-j;
  double acc = 0.0;
#pragma unroll 4
  for (int q = 0; q < 32; q++)
    acc += y[(size_t)(q>>1)*768 + p*2 + (q&1)]*Z[(size_t)col*32+q];
  U2[t] = acc / sqrt(fmax(D[col], 1e-12));
}

__global__ __launch_bounds__(TPB) void k_tail(const double* __restrict__ core,
                                              const float* __restrict__ action,
                                              const float* __restrict__ wa,
                                              const float* __restrict__ ba,
                                              const float* __restrict__ wq,
                                              const float* __restrict__ bq,
                                              float* __restrict__ out){
  __shared__ double s[TPB];
  int t = threadIdx.x;
  double v = 0.0;
  if (t < 192) {
    double av = 0.0;
#pragma unroll 4
    for (int i = 0; i < 96; i++) av += (double)action[i]*(double)wa[t*96+i];
    av += (double)ba[t];
    if (av < 0.0) av = 0.0;
    double sav = core[t] + av;
    if (sav < 0.0) sav = 0.0;
    v = sav * (double)wq[t];
  }
  s[t] = v; __syncthreads();
  for (int st = 128; st > 0; st >>= 1) { if (t < st) s[t] += s[t+st]; __syncthreads(); }
  if (t == 0) out[0] = (float)(s[0] + (double)bq[0]);
}
__global__ void k_fail(float* out){ out[0] = 1234.5f; }

// ============================ host launcher ============================
extern "C" void kernel_launch(void* const* d_in, const int* in_sizes, int n_in,
                              void* d_out, int out_size, void* d_ws, size_t ws_size,
                              hipStream_t stream){
  (void)in_sizes; (void)n_in; (void)out_size;
  const float* state  = (const float*)d_in[0];
  const float* action = (const float*)d_in[1];
  const float* conv_w = (const float*)d_in[2];
  const float* conv_b = (const float*)d_in[3];
  const float* wa     = (const float*)d_in[4];
  const float* ba     = (const float*)d_in[5];
  const float* wq     = (const float*)d_in[6];
  const float* bq     = (const float*)d_in[7];
  float* outp = (float*)d_out;

  char* ws = (char*)d_ws;
  size_t off = 0;
  auto alloc = [&](size_t bytes){ size_t o = off; off = (off + bytes + 255) & ~(size_t)255; return o; };
  size_t o_sv   = alloc(28311552ull*4);
  size_t o_A    = alloc(589824ull*8);
  size_t o_B    = alloc(49152ull*8);
  size_t o_C    = alloc(12288ull*8);
  size_t o_U0   = alloc(32*8*8);
  size_t o_U1   = alloc(96*2*8);
  size_t o_U2   = alloc(384*6*8);
  size_t o_U3   = alloc(24*2*8);
  size_t o_core = alloc(192*8);
  size_t o_G    = alloc(384ull*384*8);
  size_t o_Z    = alloc(384ull*384*8);
  size_t o_D    = alloc(384*8);
  size_t o_Tau  = alloc(384*8);
  size_t o_Sd   = alloc(384*8);
  size_t o_Se   = alloc(384*8);
  size_t o_pts  = alloc(7864320ull);   // gram partials | eigh scratch alias
  if (off > ws_size) { hipLaunchKernelGGL(k_fail, dim3(1), dim3(1), 0, stream, outp); return; }

  float*  sv   = (float*)(ws + o_sv);
  double* bufA = (double*)(ws + o_A);
  double* bufB = (double*)(ws + o_B);
  double* bufC = (double*)(ws + o_C);
  double* U0   = (double*)(ws + o_U0);
  double* U1   = (double*)(ws + o_U1);
  double* U2   = (double*)(ws + o_U2);
  double* U3   = (double*)(ws + o_U3);
  double* core = (double*)(ws + o_core);
  double* G    = (double*)(ws + o_G);
  double* Zb   = (double*)(ws + o_Z);
  double* Db   = (double*)(ws + o_D);
  double* gTau = (double*)(ws + o_Tau);
  double* gSd  = (double*)(ws + o_Sd);
  double* gSe  = (double*)(ws + o_Se);
  double* parts = (double*)(ws + o_pts);
  double* gwrk  = parts;

  auto eigh = [&](int n){
    if (n <= 96) {
      size_t shb = (size_t)2*n*n*8;
      hipLaunchKernelGGL((k_eigh_small<TPB,96>), dim3(1), dim3(TPB), shb, stream,
                         n, G, Zb, Db, gwrk);
    } else {
      hipLaunchKernelGGL((k_sytd2_big<384>), dim3(1), dim3(384), 0, stream,
                         n, G, gSd, gSe, gTau);
      hipLaunchKernelGGL((k_stedc_big<1024>), dim3(1), dim3(1024), 0, stream,
                         n, Zb, Db, gwrk, gSd, gSe);
      // only top-8 eigenvector columns are consumed downstream (k_fact_sq r=6)
      hipLaunchKernelGGL(k_ormtr_big, dim3(1), dim3(256), 0, stream,
                         n, G, Zb, gTau, n - OB_COLS);
    }
  };

  hipLaunchKernelGGL(k_conv, dim3(110592), dim3(TPB), 0, stream, state, conv_w, conv_b, sv);

  // ---- init HOSVD factors ----
  hipLaunchKernelGGL(k_g0p, dim3(288), dim3(TPB), 0, stream, sv, parts);
  hipLaunchKernelGGL(k_reduce, dim3(4), dim3(TPB), 0, stream, G, parts, 288, 1024);
  eigh(32);
  hipLaunchKernelGGL(k_fact_sq, dim3(1), dim3(TPB), 0, stream, U0, Zb, 32, 8);

  hipLaunchKernelGGL(k_g1p, dim3(32), dim3(TPB), 0, stream, sv, parts);
  hipLaunchKernelGGL(k_reduce, dim3(36), dim3(TPB), 0, stream, G, parts, 32, 9216);
  eigh(96);
  hipLaunchKernelGGL(k_fact_sq, dim3(1), dim3(TPB), 0, stream, U1, Zb, 96, 2);

  hipLaunchKernelGGL(k_g2p, dim3(G2_NKG*36), dim3(TPB), 0, stream, sv, parts);
  hipLaunchKernelGGL(k_reduce, dim3(576), dim3(TPB), 0, stream, G, parts, G2_NKG, 147456);
  eigh(384);
  hipLaunchKernelGGL(k_fact_sq, dim3(9), dim3(TPB), 0, stream, U2, Zb, 384, 6);

  hipLaunchKernelGGL(k_g3p, dim3(128), dim3(TPB), 0, stream, sv, parts);
  hipLaunchKernelGGL(k_reduce, dim3(3), dim3(TPB), 0, stream, G, parts, 128, 576);
  eigh(24);
  hipLaunchKernelGGL(k_fact_sq, dim3(1), dim3(TPB), 0, stream, U3, Zb, 24, 2);

  // ---- HOOI sweeps ----
  for (int s = 0; s < 5; s++) {
    // n=0 : project order [2,1,3]
    hipLaunchKernelGGL(k_c2sv, dim3(3072), dim3(TPB), 0, stream, sv, U2, bufA);
    hipLaunchKernelGGL(k_contract4, dim3(36), dim3(TPB), 0, stream, bufA, U1, bufB, 32,96,6,24, 1, 2);
    hipLaunchKernelGGL(k_contract4, dim3(3),  dim3(TPB), 0, stream, bufB, U3, bufC, 32,2,6,24, 3, 2);
    hipLaunchKernelGGL(k_gram_sw0, dim3(1), dim3(TPB), 0, stream, bufC, G);
    eigh(24);
    hipLaunchKernelGGL(k_factT0, dim3(1), dim3(TPB), 0, stream, U0, bufC, Zb, Db);
    // n=1 : [2,3,0]
    hipLaunchKernelGGL(k_c2sv, dim3(3072), dim3(TPB), 0, stream, sv, U2, bufA);
    hipLaunchKernelGGL(k_contract4, dim3(144), dim3(TPB), 0, stream, bufA, U3, bufB, 32,96,6,24, 3, 2);
    hipLaunchKernelGGL(k_contract4, dim3(36),  dim3(TPB), 0, stream, bufB, U0, bufC, 32,96,6,2, 0, 8);
    hipLaunchKernelGGL(k_gram_sw1, dim3(1), dim3(TPB), 0, stream, bufC, G);
    eigh(96);
    hipLaunchKernelGGL(k_fact_sq, dim3(1), dim3(TPB), 0, stream, U1, Zb, 96, 2);
    // n=2 : [1,3,0]
    hipLaunchKernelGGL(k_c1sv, dim3(1152), dim3(TPB), 0, stream, sv, U1, bufA);
    hipLaunchKernelGGL(k_contract4, dim3(192), dim3(TPB), 0, stream, bufA, U3, bufB, 32,2,384,24, 3, 2);
    hipLaunchKernelGGL(k_contract4, dim3(48),  dim3(TPB), 0, stream, bufB, U0, bufC, 32,2,384,2, 0, 8);
    hipLaunchKernelGGL(k_gram_sw2, dim3(1), dim3(TPB), 0, stream, bufC, G);
    eigh(32);
    hipLaunchKernelGGL(k_factT2, dim3(9), dim3(TPB), 0, stream, U2, bufC, Zb, Db);
    // n=3 : [2,1,0]
    hipLaunchKernelGGL(k_c2sv, dim3(3072), dim3(TPB), 0, stream, sv, U2, bufA);
    hipLaunchKernelGGL(k_contract4, dim3(36), dim3(TPB), 0, stream, bufA, U1, bufB, 32,96,6,24, 1, 2);
    hipLaunchKernelGGL(k_contract4, dim3(9),  dim3(TPB), 0, stream, bufB, U0, bufC, 32,2,6,24, 0, 8);
    hipLaunchKernelGGL(k_gram_sw3, dim3(1), dim3(TPB), 0, stream, bufC, G);
    eigh(24);
    hipLaunchKernelGGL(k_fact_sq, dim3(1), dim3(TPB), 0, stream, U3, Zb, 24, 2);
  }

  // ---- core : [2,1,3,0] ----
  hipLaunchKernelGGL(k_c2sv, dim3(3072), dim3(TPB), 0, stream, sv, U2, bufA);
  hipLaunchKernelGGL(k_contract4, dim3(36), dim3(TPB), 0, stream, bufA, U1, bufB, 32,96,6,24, 1, 2);
  hipLaunchKernelGGL(k_contract4, dim3(3),  dim3(TPB), 0, stream, bufB, U3, bufC, 32,2,6,24, 3, 2);
  hipLaunchKernelGGL(k_contract4, dim3(1),  dim3(TPB), 0, stream, bufC, U0, core, 32,2,6,2, 0, 8);

  hipLaunchKernelGGL(k_tail, dim3(1), dim3(TPB), 0, stream, core, action, wa, ba, wq, bq, outp);
}

// Round 9
// 69525.446 us; speedup vs baseline: 1.1387x; 1.1387x over previous
//
#include <hip/hip_runtime.h>
#include <math.h>

#define TPB 256
#define SMLSIZ 25
#define D_EPS    1.1102230246251565e-16
#define D_SAFMIN 2.2250738585072014e-308
#define CMDMAX 8192
#define SCHUNK 64
#define MLEV 4
#define MAXTASK 16
#define MERGE_CMD 512
#define GWRK_DBL 983040
#define CMDTOP_DBL (GWRK_DBL - MAXTASK*MERGE_CMD*3)   // 958464

// ============================ small LAPACK helpers ============================
__device__ __forceinline__ double d_sign(double a, double b){
  double aa = fabs(a);
  return (b >= 0.0) ? aa : -aa;
}
__device__ __forceinline__ double dlapy2(double x, double y){
  double xa = fabs(x), ya = fabs(y);
  double w = fmax(xa, ya), z = fmin(xa, ya);
  if (z == 0.0) return w;
  double t = z / w;
  return w * sqrt(1.0 + t*t);
}
// LAPACK >= 3.10 dlartg
__device__ void dlartg(double f, double g, double* cs, double* sn, double* r){
  if (g == 0.0) { *cs = 1.0; *sn = 0.0; *r = f; return; }
  if (f == 0.0) { *cs = 0.0; *sn = (g >= 0.0) ? 1.0 : -1.0; *r = fabs(g); return; }
  double f1 = fabs(f), g1 = fabs(g);
  double rtmin = sqrt(D_SAFMIN);
  double rtmax = sqrt(1.0/(2.0*D_SAFMIN));
  if (f1 > rtmin && f1 < rtmax && g1 > rtmin && g1 < rtmax) {
    double d = sqrt(f*f + g*g);
    *cs = f1 / d;
    double rr = (f >= 0.0) ? d : -d;
    *sn = g / rr;
    *r = rr;
  } else {
    double safmax = 1.0/D_SAFMIN;
    double u = fmin(safmax, fmax(fmax(D_SAFMIN, f1), g1));
    double fs = f/u, gs = g/u;
    double d = sqrt(fs*fs + gs*gs);
    *cs = fabs(fs)/d;
    double rr = (f >= 0.0) ? d : -d;
    *sn = gs / rr;
    *r = rr * u;
  }
}
__device__ void dlaev2(double a, double b, double c,
                       double* rt1, double* rt2, double* cs1, double* sn1){
  double sm = a + c, df = a - c, adf = fabs(df), tb = b + b, ab = fabs(tb);
  double acmx, acmn;
  if (fabs(a) > fabs(c)) { acmx = a; acmn = c; } else { acmx = c; acmn = a; }
  double rt;
  if (adf > ab)      { double t = ab/adf; rt = adf*sqrt(1.0+t*t); }
  else if (adf < ab) { double t = adf/ab; rt = ab*sqrt(1.0+t*t); }
  else               rt = ab*sqrt(2.0);
  int sgn1;
  if (sm < 0.0)      { *rt1 = 0.5*(sm-rt); sgn1 = -1; *rt2 = (acmx / *rt1)*acmn - (b / *rt1)*b; }
  else if (sm > 0.0) { *rt1 = 0.5*(sm+rt); sgn1 =  1; *rt2 = (acmx / *rt1)*acmn - (b / *rt1)*b; }
  else               { *rt1 = 0.5*rt; *rt2 = -0.5*rt; sgn1 = 1; }
  int sgn2; double cs;
  if (df >= 0.0) { cs = df + rt; sgn2 = 1; } else { cs = df - rt; sgn2 = -1; }
  double acs = fabs(cs);
  if (acs > ab) {
    double ct = -tb/cs;
    *sn1 = 1.0/sqrt(1.0+ct*ct);
    *cs1 = ct * (*sn1);
  } else {
    if (ab == 0.0) { *cs1 = 1.0; *sn1 = 0.0; }
    else { double tn = -cs/tb; *cs1 = 1.0/sqrt(1.0+tn*tn); *sn1 = tn * (*cs1); }
  }
  if (sgn1 == sgn2) { double tn = *cs1; *cs1 = -(*sn1); *sn1 = tn; }
}
__device__ void dlamrg(int n1, int n2, const double* a, int s1, int s2, int* idx){
  int n1sv = n1, n2sv = n2;
  int ind1 = (s1 > 0) ? 0 : n1-1;
  int ind2 = (s2 > 0) ? n1 : n1+n2-1;
  int i = 0;
  while (n1sv > 0 && n2sv > 0) {
    if (a[ind1] <= a[ind2]) { idx[i++] = ind1; ind1 += s1; n1sv--; }
    else                    { idx[i++] = ind2; ind2 += s2; n2sv--; }
  }
  while (n1sv > 0) { idx[i++] = ind1; ind1 += s1; n1sv--; }
  while (n2sv > 0) { idx[i++] = ind2; ind2 += s2; n2sv--; }
}

__device__ void my_laed5(int i, const double* d, const double* z, double rho,
                         double* delta, double* lam){
  double del = d[1]-d[0];
  if (i == 0) {
    double w = 1.0 + 2.0*rho*(z[1]*z[1]-z[0]*z[0])/del;
    if (w > 0.0) {
      double b = del + rho*(z[0]*z[0]+z[1]*z[1]);
      double c = rho*z[0]*z[0]*del;
      double tau = 2.0*c/(b+sqrt(fabs(b*b-4.0*c)));
      *lam = d[0] + tau;
      delta[0] = -z[0]/tau;
      delta[1] =  z[1]/(del-tau);
    } else {
      double b = -del + rho*(z[0]*z[0]+z[1]*z[1]);
      double c = rho*z[1]*z[1]*del;
      double tau;
      if (b > 0.0) tau = -2.0*c/(b+sqrt(b*b+4.0*c));
      else         tau = (b - sqrt(b*b+4.0*c))/2.0;
      *lam = d[1] + tau;
      delta[0] = -z[0]/(del+tau);
      delta[1] = -z[1]/tau;
    }
    double temp = dlapy2(delta[0], delta[1]);
    delta[0] /= temp; delta[1] /= temp;
  } else {
    double b = -del + rho*(z[0]*z[0]+z[1]*z[1]);
    double c = rho*z[1]*z[1]*del;
    double tau;
    if (b > 0.0) tau = (b+sqrt(b*b+4.0*c))/2.0;
    else         tau = 2.0*c/(-b+sqrt(b*b+4.0*c));
    *lam = d[1] + tau;
    delta[0] = -z[0]/(del+tau);
    delta[1] = -z[1]/tau;
    double temp = dlapy2(delta[0], delta[1]);
    delta[0] /= temp; delta[1] /= temp;
  }
}
__device__ void my_laed4(int k, int j, const double* dl, const double* w, double rho,
                         double* delta, double* lam){
  if (k == 1) { *lam = dl[0] + rho*w[0]*w[0]; delta[0] = 1.0; return; }
  if (k == 2) { my_laed5(j, dl, w, rho, delta, lam); return; }
  int base; double a, b;
  if (j < k-1) {
    double dj = dl[j], dj1 = dl[j+1];
    double mid = 0.5*(dj+dj1);
    double fm = 1.0;
#pragma unroll 4
    for (int i = 0; i < k; i++) fm += rho*w[i]*w[i]/(dl[i]-mid);
    if (fm >= 0.0) { base = j;   a = 0.0;      b = mid - dj;  }
    else           { base = j+1; a = mid - dj1; b = 0.0;      }
  } else {
    base = k-1;
    double zz = 0.0;
#pragma unroll 4
    for (int i = 0; i < k; i++) zz += w[i]*w[i];
    a = 0.0; b = rho*zz;
    for (int t = 0; t < 64; t++) {
      double g = 1.0;
#pragma unroll 4
      for (int i = 0; i < k; i++) g += rho*w[i]*w[i]/((dl[i]-dl[base]) - b);
      if (g >= 0.0) break;
      b *= 2.0;
    }
  }
  for (int it = 0; it < 140; it++) {
    double m = 0.5*(a+b);
    if (m == a || m == b) break;
    double g = 1.0;
#pragma unroll 4
    for (int i = 0; i < k; i++) g += rho*w[i]*w[i]/((dl[i]-dl[base]) - m);
    if (g >= 0.0) b = m; else a = m;
  }
  double tau = 0.5*(a+b);
  *lam = dl[base] + tau;
#pragma unroll 4
  for (int i = 0; i < k; i++) delta[i] = (dl[i]-dl[base]) - tau;
}

// ============================ STEQR scan (serial, rotation recorder) ============================
struct Cmd { double c, s; int a, b; };   // b<0: rotation on cols (a,a+1); else swap cols a,b

#define REC_CMD(CC,SS,AA,BB) do{ if (ncmd < cmax){ cbuf[ncmd].c=(CC); cbuf[ncmd].s=(SS); cbuf[ncmd].a=(AA); cbuf[ncmd].b=(BB);} ncmd++; }while(0)

__device__ int steqr_scan(int m, double* sd_, double* se_, Cmd* cbuf, int cmax){
  int ncmd = 0;
  const double eps = D_EPS, eps2 = D_EPS*D_EPS, safmin = D_SAFMIN;
  const double ssfmax = sqrt(1.7976931348623157e308)/3.0;
  const double ssfmin = sqrt(D_SAFMIN)/(D_EPS*D_EPS);
  int nmaxit = m*30, jtot = 0;
  int l1 = 0;
  bool noSort = false;
  while (1) {
    if (l1 > m-1) break;
    if (l1 > 0) se_[l1-1] = 0.0;
    int mm = m-1;
    for (int mi = l1; mi <= m-2; mi++) {
      double tst = fabs(se_[mi]);
      if (tst == 0.0) { mm = mi; break; }
      if (tst <= (sqrt(fabs(sd_[mi]))*sqrt(fabs(sd_[mi+1])))*eps) { se_[mi] = 0.0; mm = mi; break; }
    }
    int l = l1, lsv = l, lend = mm, lendsv = lend;
    l1 = mm+1;
    if (lend == l) continue;
    double anorm = 0.0;
    for (int i = l; i <= lend; i++) anorm = fmax(anorm, fabs(sd_[i]));
    for (int i = l; i <  lend; i++) anorm = fmax(anorm, fabs(se_[i]));
    if (anorm == 0.0) continue;
    int iscale = 0;
    if (anorm > ssfmax) { iscale = 1; double f = ssfmax/anorm;
      for (int i = l; i <= lend; i++) sd_[i] *= f;
      for (int i = l; i <  lend; i++) se_[i] *= f; }
    else if (anorm < ssfmin) { iscale = 2; double f = ssfmin/anorm;
      for (int i = l; i <= lend; i++) sd_[i] *= f;
      for (int i = l; i <  lend; i++) se_[i] *= f; }
    if (fabs(sd_[lend]) < fabs(sd_[l])) { int t = l; l = lend; lend = t; }
    if (lend > l) {
      // QL
      while (1) {
        int mq = lend;
        if (l != lend) {
          for (int mi = l; mi <= lend-1; mi++) {
            double tst = se_[mi]*se_[mi];
            if (tst <= (eps2*fabs(sd_[mi]))*fabs(sd_[mi+1]) + safmin) { mq = mi; break; }
          }
        }
        if (mq < lend) se_[mq] = 0.0;
        double p = sd_[l];
        if (mq == l) { sd_[l] = p; l++; if (l <= lend) continue; break; }
        if (mq == l+1) {
          double rt1, rt2, cc, ss;
          dlaev2(sd_[l], se_[l], sd_[l+1], &rt1, &rt2, &cc, &ss);
          REC_CMD(cc, ss, l, -1);
          sd_[l] = rt1; sd_[l+1] = rt2; se_[l] = 0.0;
          l += 2; if (l <= lend) continue; break;
        }
        if (jtot == nmaxit) break;
        jtot++;
        double g = (sd_[l+1]-p)/(2.0*se_[l]);
        double r = dlapy2(g, 1.0);
        g = sd_[mq] - p + se_[l]/(g + d_sign(r, g));
        double ss = 1.0, cc = 1.0; p = 0.0;
        for (int i = mq-1; i >= l; i--) {
          double ff = ss*se_[i], bb = cc*se_[i];
          dlartg(g, ff, &cc, &ss, &r);
          if (i != mq-1) se_[i+1] = r;
          g = sd_[i+1] - p;
          r = (sd_[i]-g)*ss + 2.0*cc*bb;
          p = ss*r;
          sd_[i+1] = g + p;
          g = cc*r - bb;
          REC_CMD(cc, -ss, i, -1);
        }
        sd_[l] -= p; se_[l] = g;
      }
    } else {
      // QR
      while (1) {
        int mq = lend;
        if (l != lend) {
          for (int mi = l; mi >= lend+1; mi--) {
            double tst = se_[mi-1]*se_[mi-1];
            if (tst <= (eps2*fabs(sd_[mi]))*fabs(sd_[mi-1]) + safmin) { mq = mi; break; }
          }
        }
        if (mq > lend) se_[mq-1] = 0.0;
        double p = sd_[l];
        if (mq == l) { sd_[l] = p; l--; if (l >= lend) continue; break; }
        if (mq == l-1) {
          double rt1, rt2, cc, ss;
          dlaev2(sd_[l-1], se_[l-1], sd_[l], &rt1, &rt2, &cc, &ss);
          REC_CMD(cc, ss, l-1, -1);
          sd_[l-1] = rt1; sd_[l] = rt2; se_[l-1] = 0.0;
          l -= 2; if (l >= lend) continue; break;
        }
        if (jtot == nmaxit) break;
        jtot++;
        double g = (sd_[l-1]-p)/(2.0*se_[l-1]);
        double r = dlapy2(g, 1.0);
        g = sd_[mq] - p + se_[l-1]/(g + d_sign(r, g));
        double ss = 1.0, cc = 1.0; p = 0.0;
        for (int i = mq; i <= l-1; i++) {
          double ff = ss*se_[i], bb = cc*se_[i];
          dlartg(g, ff, &cc, &ss, &r);
          if (i != mq) se_[i-1] = r;
          g = sd_[i] - p;
          r = (sd_[i+1]-g)*ss + 2.0*cc*bb;
          p = ss*r;
          sd_[i] = g + p;
          g = cc*r - bb;
          REC_CMD(cc, ss, i, -1);
        }
        sd_[l] -= p; se_[l-1] = g;
      }
    }
    if (iscale == 1) { double f = anorm/ssfmax;
      for (int i = lsv; i <= lendsv; i++) sd_[i] *= f;
      for (int i = lsv; i <  lendsv; i++) se_[i] *= f; }
    else if (iscale == 2) { double f = anorm/ssfmin;
      for (int i = lsv; i <= lendsv; i++) sd_[i] *= f;
      for (int i = lsv; i <  lendsv; i++) se_[i] *= f; }
    if (jtot >= nmaxit) { noSort = true; break; }
  }
  if (!noSort) {
    for (int ii = 1; ii <= m-1; ii++) {
      int i = ii-1, kk = i; double p = sd_[i];
      for (int j = ii; j <= m-1; j++) if (sd_[j] < p) { kk = j; p = sd_[j]; }
      if (kk != i) {
        sd_[kk] = sd_[i]; sd_[i] = p;
        REC_CMD(0.0, 0.0, i, kk);
      }
    }
  }
  return (ncmd <= cmax) ? ncmd : cmax;
}

// apply one command to column-pair at row r (ld = column stride)
__device__ __forceinline__ void apply_cmd(const Cmd& cm, double* z, int ld, int r){
  if (cm.b < 0) {
    double t1 = z[(size_t)(cm.a+1)*ld + r];
    double t0 = z[(size_t)cm.a*ld + r];
    z[(size_t)(cm.a+1)*ld + r] = cm.c*t1 - cm.s*t0;
    z[(size_t)cm.a*ld + r]     = cm.s*t1 + cm.c*t0;
  } else {
    double t0 = z[(size_t)cm.a*ld + r];
    z[(size_t)cm.a*ld + r] = z[(size_t)cm.b*ld + r];
    z[(size_t)cm.b*ld + r] = t0;
  }
}

// ============================ STEQR (direct path: scan + chunked replay) ============================
template<int NT>
__device__ void dev_steqr(int m, double* sd_, double* se_, double* z, int ldz,
                          Cmd* cbuf, int* icom, Cmd* scmd){
  const int tid = threadIdx.x;
  for (int x = tid; x < m*m; x += NT) z[(size_t)(x/m)*ldz + (x%m)] = ((x/m) == (x%m)) ? 1.0 : 0.0;
  __syncthreads();
  if (m <= 1) return;
  if (tid == 0) icom[0] = steqr_scan(m, sd_, se_, cbuf, CMDMAX);
  __syncthreads();
  int ncmd = icom[0];
  for (int base = 0; base < ncmd; base += SCHUNK) {
    int cnt = ncmd - base; if (cnt > SCHUNK) cnt = SCHUNK;
    for (int q = tid; q < cnt; q += NT) scmd[q] = cbuf[base+q];
    __syncthreads();
    for (int r = tid; r < m; r += NT)
#pragma unroll 2
      for (int q = 0; q < cnt; q++) apply_cmd(scmd[q], z, ldz, r);
    __syncthreads();
  }
}

// ============================ SYTD2 (lower, unblocked; LDS A for small) ============================
template<int NT>
__device__ void sytd2_dev(int n, double* A, double* sd, double* se, double* stau,
                          double* szv, double* red, double* dcom){
  const int tid = threadIdx.x;
  for (int i = 0; i < n-1; i++) {
    double part = 0.0;
#pragma unroll 4
    for (int r = i+2+tid; r < n; r += NT) { double v = A[(size_t)i*n + r]; part += v*v; }
    red[tid] = part; __syncthreads();
    for (int s = NT/2; s > 0; s >>= 1) { if (tid < s) red[tid] += red[tid+s]; __syncthreads(); }
    if (tid == 0) {
      double xnorm = sqrt(red[0]);
      double alpha = A[(size_t)i*n + i + 1];
      double taui, scalf = 0.0;
      if (xnorm == 0.0) { taui = 0.0; se[i] = alpha; }
      else {
        double beta = -d_sign(dlapy2(alpha, xnorm), alpha);
        taui = (beta - alpha)/beta;
        scalf = 1.0/(alpha - beta);
        se[i] = beta;
      }
      stau[i] = taui; dcom[0] = taui; dcom[1] = scalf;
    }
    __syncthreads();
    double taui = dcom[0];
    if (taui != 0.0) {
      double scalf = dcom[1];
      for (int r = i+2+tid; r < n; r += NT) A[(size_t)i*n + r] *= scalf;
      __syncthreads();
      if (tid == 0) A[(size_t)i*n + i + 1] = 1.0;
      __syncthreads();
      for (int r = i+1+tid; r < n; r += NT) {
        double acc = 0.0;
#pragma unroll 4
        for (int c = i+1; c <= r; c++) acc += A[(size_t)c*n + r] * A[(size_t)i*n + c];
#pragma unroll 4
        for (int c = r+1; c < n; c++)  acc += A[(size_t)r*n + c] * A[(size_t)i*n + c];
        szv[r] = taui * acc;
      }
      __syncthreads();
      double p2 = 0.0;
#pragma unroll 4
      for (int r = i+1+tid; r < n; r += NT) p2 += szv[r] * A[(size_t)i*n + r];
      red[tid] = p2; __syncthreads();
      for (int s = NT/2; s > 0; s >>= 1) { if (tid < s) red[tid] += red[tid+s]; __syncthreads(); }
      double alpha2 = -0.5*taui*red[0];
      __syncthreads();
      for (int r = i+1+tid; r < n; r += NT) szv[r] += alpha2 * A[(size_t)i*n + r];
      __syncthreads();
      for (int c = i+1+tid; c < n; c += NT) {
        double vc = A[(size_t)i*n + c], wc = szv[c];
#pragma unroll 4
        for (int r = c; r < n; r++)
          A[(size_t)c*n + r] -= A[(size_t)i*n + r]*wc + szv[r]*vc;
      }
      __syncthreads();
      if (tid == 0) A[(size_t)i*n + i + 1] = se[i];
    }
    __syncthreads();
    if (tid == 0) sd[i] = A[(size_t)i*n + i];
    __syncthreads();
  }
  if (tid == 0) sd[n-1] = A[(size_t)(n-1)*n + (n-1)];
  __syncthreads();
}

// ============================ block reduce (shfl + one LDS pass) ============================
template<int NT>
__device__ __forceinline__ double block_sum(double v, double* red){
  for (int off = 32; off > 0; off >>= 1) v += __shfl_down(v, off);
  const int wid = threadIdx.x >> 6, lane = threadIdx.x & 63;
  __syncthreads();
  if (lane == 0) red[wid] = v;
  __syncthreads();
  if (threadIdx.x == 0) {
    double s = 0.0;
    for (int w = 0; w < NT/64; w++) s += red[w];
    red[0] = s;
  }
  __syncthreads();
  return red[0];
}

// ============================ SYTD2 for big n (full-symmetric A, coalesced) ============================
template<int NT>
__device__ void sytd2_big(int n, double* A, double* sd, double* se, double* stau,
                          double* vv, double* ww, double* red, double* dcom){
  const int tid = threadIdx.x;
  for (int i = 0; i < n-1; i++) {
    const int i1 = i+1;
    double part = 0.0;
#pragma unroll 4
    for (int r = i+2+tid; r < n; r += NT) { double v = A[(size_t)i*n + r]; part += v*v; }
    double nrm2 = block_sum<NT>(part, red);
    if (tid == 0) {
      double xnorm = sqrt(nrm2);
      double alpha = A[(size_t)i*n + i + 1];
      double taui, scalf = 0.0;
      if (xnorm == 0.0) { taui = 0.0; se[i] = alpha; }
      else {
        double beta = -d_sign(dlapy2(alpha, xnorm), alpha);
        taui = (beta - alpha)/beta;
        scalf = 1.0/(alpha - beta);
        se[i] = beta;
      }
      stau[i] = taui; dcom[0] = taui; dcom[1] = scalf;
    }
    __syncthreads();
    double taui = dcom[0];
    if (taui != 0.0) {
      double scalf = dcom[1];
      for (int r = i+2+tid; r < n; r += NT) {
        double v = A[(size_t)i*n + r] * scalf;
        A[(size_t)i*n + r] = v;
        vv[r] = v;
      }
      if (tid == 0) vv[i1] = 1.0;
      __syncthreads();
      for (int r = i1 + tid; r < n; r += NT) {
        double acc = 0.0;
        int c = i1;
        int rem = (n - i1) & 7;
        for (; c < i1 + rem; c++) acc += A[(size_t)c*n + r] * vv[c];
        for (; c < n; c += 8) {
          double x0 = A[(size_t)(c+0)*n + r], x1 = A[(size_t)(c+1)*n + r];
          double x2 = A[(size_t)(c+2)*n + r], x3 = A[(size_t)(c+3)*n + r];
          double x4 = A[(size_t)(c+4)*n + r], x5 = A[(size_t)(c+5)*n + r];
          double x6 = A[(size_t)(c+6)*n + r], x7 = A[(size_t)(c+7)*n + r];
          double v0 = vv[c+0], v1 = vv[c+1], v2 = vv[c+2], v3 = vv[c+3];
          double v4 = vv[c+4], v5 = vv[c+5], v6 = vv[c+6], v7 = vv[c+7];
          acc += x0*v0; acc += x1*v1; acc += x2*v2; acc += x3*v3;
          acc += x4*v4; acc += x5*v5; acc += x6*v6; acc += x7*v7;
        }
        ww[r] = taui * acc;
      }
      __syncthreads();
      double p2 = 0.0;
#pragma unroll 4
      for (int r = i1+tid; r < n; r += NT) p2 += ww[r] * vv[r];
      double dotvw = block_sum<NT>(p2, red);
      double alpha2 = -0.5*taui*dotvw;
      for (int r = i1+tid; r < n; r += NT) ww[r] += alpha2 * vv[r];
      __syncthreads();
      {
        const int m = n - i1;
        const long tot = (long)m*m;
#pragma unroll 4
        for (long x = tid; x < tot; x += NT) {
          int c = i1 + (int)(x / m);
          int r = i1 + (int)(x % m);
          A[(size_t)c*n + r] -= vv[r]*ww[c] + ww[r]*vv[c];
        }
      }
      __syncthreads();
    }
    if (tid == 0) sd[i] = A[(size_t)i*n + i];
    __syncthreads();
  }
  if (tid == 0) sd[n-1] = A[(size_t)(n-1)*n + (n-1)];
  __syncthreads();
}

// ============================ STEDC (monolithic; used by small eighs only) ============================
template<int NT>
__device__ void stedc_dev(int n, double* Z, double* gwrk,
                          double* sd, double* se, double* sdl, double* sw,
                          double* szv, double* ss2, double* dcom,
                          int* indx, int* indxc, int* indxp, int* coltyp,
                          int* indxq, int* iw, int* icom, int* icom2, Cmd* scmd){
  const int tid = threadIdx.x;
  double* q2   = gwrk;
  double* sbuf = gwrk + (size_t)n*n;
  double* qtmp = gwrk + 2*(size_t)n*n;
  double* dtmp = qtmp + (size_t)n*n;
  Cmd* cbuf = (Cmd*)(dtmp + n + 16);

  if (n <= SMLSIZ) {
    dev_steqr<NT>(n, sd, se, Z, n, cbuf, icom, scmd);
    return;
  }
  int startb = 0, nblk = 0;
  while (startb < n) {
    int finish = startb;
    while (finish < n-1) {
      double tiny = D_EPS*sqrt(fabs(sd[finish]))*sqrt(fabs(sd[finish+1]));
      if (fabs(se[finish]) > tiny) finish++; else break;
    }
    int msz = finish - startb + 1;
    nblk++;
    if (msz == 1) { startb = finish+1; continue; }
    if (msz <= SMLSIZ) {
      dev_steqr<NT>(msz, sd+startb, se+startb, Z + (size_t)startb*n + startb, n, cbuf, icom, scmd);
      startb = finish+1; continue;
    }
    if (tid == 0) {
      double onrm = 0.0;
      for (int i = startb; i <= finish; i++) onrm = fmax(onrm, fabs(sd[i]));
      for (int i = startb; i <  finish; i++) onrm = fmax(onrm, fabs(se[i]));
      if (onrm == 0.0) onrm = 1.0;
      dcom[7] = onrm;
      double inv = 1.0/onrm;
      for (int i = startb; i <= finish; i++) sd[i] *= inv;
      for (int i = startb; i <  finish; i++) se[i] *= inv;
    }
    __syncthreads();
    if (tid == 0) {
      iw[0] = msz; int sp0 = 1;
      while (iw[sp0-1] > SMLSIZ) {
        for (int j = sp0-1; j >= 0; j--) { iw[2*j+1] = (iw[j]+1)/2; iw[2*j] = iw[j]/2; }
        sp0 *= 2;
      }
      for (int j = 1; j < sp0; j++) iw[j] += iw[j-1];
      icom[8] = sp0;
      for (int i = 0; i < sp0-1; i++) {
        int bb = startb + iw[i] - 1;
        sd[bb]   -= fabs(se[bb]);
        sd[bb+1] -= fabs(se[bb]);
      }
    }
    __syncthreads();
    int sp = icom[8];
    {
      const int wid = tid >> 6, lane = tid & 63;
      const int nwaves = NT/64;
      for (int li = wid; li < sp; li += nwaves) {
        if (lane == 0) {
          int submat = (li == 0) ? 0 : iw[li-1];
          int matsiz = iw[li] - submat;
          icom2[li] = (matsiz > 1)
            ? steqr_scan(matsiz, sd+startb+submat, se+startb+submat, cbuf + (size_t)li*CMDMAX, CMDMAX)
            : 0;
        }
      }
      __syncthreads();
      for (int li = wid; li < sp; li += nwaves) {
        int submat = (li == 0) ? 0 : iw[li-1];
        int matsiz = iw[li] - submat;
        int nc = icom2[li];
        double* zb = Z + (size_t)(startb+submat)*n + (startb+submat);
        Cmd* cb = cbuf + (size_t)li*CMDMAX;
        if (lane < matsiz) {
#pragma unroll 2
          for (int q = 0; q < nc; q++) apply_cmd(cb[q], zb, n, lane);
        }
      }
      __syncthreads();
      for (int x = tid; x < msz; x += NT) {
        int sub = 0;
        for (int t = 0; t < sp; t++) { if (x < iw[t]) { sub = (t == 0) ? 0 : iw[t-1]; break; } }
        indxq[startb + x] = x - sub;
      }
      __syncthreads();
    }
    while (sp > 1) {
      for (int i2 = 0; i2 <= sp-2; i2 += 2) {
        int submat, matsiz, msd2;
        if (i2 == 0) { submat = 0; matsiz = iw[1]; msd2 = iw[0]; }
        else { submat = iw[i2-1]; matsiz = iw[i2+1]-iw[i2-1]; msd2 = matsiz/2; }
        {
          const int nm = matsiz, n1 = msd2, ldn = n;
          double* dm = sd + startb + submat;
          double* qb = Z + (size_t)(startb+submat)*n + (startb+submat);
          int* ixq = indxq + startb + submat;
          double rho_in = se[startb+submat+msd2-1];
          for (int i = tid; i < n1; i += NT)      szv[i] = qb[(size_t)i*ldn + (n1-1)];
          for (int i = n1+tid; i < nm; i += NT)   szv[i] = qb[(size_t)i*ldn + n1];
          __syncthreads();
          if (tid == 0) {
            int nrot = 0;
            const int n2_ = nm - n1;
            double rho = rho_in;
            if (rho < 0.0) for (int i = n1; i < nm; i++) szv[i] = -szv[i];
            double tsc = 1.0/sqrt(2.0);
            for (int i = 0; i < nm; i++) szv[i] *= tsc;
            rho = fabs(2.0*rho);
            dcom[0] = rho;
            for (int i = n1; i < nm; i++) ixq[i] += n1;
            for (int i = 0; i < nm; i++) sdl[i] = dm[ixq[i]];
            dlamrg(n1, n2_, sdl, 1, 1, indxc);
            for (int i = 0; i < nm; i++) indx[i] = ixq[indxc[i]];
            int imax = 0, jmax = 0;
            for (int i = 1; i < nm; i++) {
              if (fabs(szv[i]) > fabs(szv[imax])) imax = i;
              if (fabs(dm[i])  > fabs(dm[jmax]))  jmax = i;
            }
            double tol = 8.0*D_EPS*fmax(fabs(dm[jmax]), fabs(szv[imax]));
            if (rho*fabs(szv[imax]) <= tol) {
              icom[1] = 0;
              for (int j = 0; j < nm; j++) sdl[j] = dm[indx[j]];
            } else {
              for (int i = 0; i < n1; i++) coltyp[i] = 0;
              for (int i = n1; i < nm; i++) coltyp[i] = 2;
              int k = 0, k2 = nm;
              int pj = 0, jj = 0;
              bool haveP = false;
              for (jj = 0; jj < nm; jj++) {
                int nj = indx[jj];
                if (rho*fabs(szv[nj]) <= tol) { k2--; coltyp[nj] = 3; indxp[k2] = nj; }
                else { pj = nj; haveP = true; jj++; break; }
              }
              if (haveP) {
                while (1) {
                  if (jj > nm-1) break;
                  int nj = indx[jj];
                  if (rho*fabs(szv[nj]) <= tol) { k2--; coltyp[nj] = 3; indxp[k2] = nj; }
                  else {
                    double s_ = szv[pj], c_ = szv[nj];
                    double tau = dlapy2(c_, s_);
                    double tdf = dm[nj] - dm[pj];
                    c_ = c_/tau; s_ = -s_/tau;
                    if (fabs(tdf*c_*s_) <= tol) {
                      szv[nj] = tau; szv[pj] = 0.0;
                      if (coltyp[nj] != coltyp[pj]) coltyp[nj] = 1;
                      coltyp[pj] = 3;
                      if (nrot < CMDMAX) { cbuf[nrot].c = c_; cbuf[nrot].s = s_; cbuf[nrot].a = pj; cbuf[nrot].b = nj; }
                      nrot++;
                      double t2 = dm[pj]*c_*c_ + dm[nj]*s_*s_;
                      dm[nj] = dm[pj]*s_*s_ + dm[nj]*c_*c_;
                      dm[pj] = t2;
                      k2--;
                      int i1 = 1;
                      while (1) {
                        if (k2 + i1 <= nm-1) {
                          if (dm[pj] < dm[indxp[k2+i1]]) {
                            indxp[k2+i1-1] = indxp[k2+i1];
                            indxp[k2+i1] = pj;
                            i1++;
                          } else { indxp[k2+i1-1] = pj; break; }
                        } else { indxp[k2+i1-1] = pj; break; }
                      }
                      pj = nj;
                    } else {
                      k++; sdl[k-1] = dm[pj]; sw[k-1] = szv[pj]; indxp[k-1] = pj; pj = nj;
                    }
                  }
                  jj++;
                }
                k++; sdl[k-1] = dm[pj]; sw[k-1] = szv[pj]; indxp[k-1] = pj;
              }
              int ct[4] = {0,0,0,0};
              for (int j = 0; j < nm; j++) ct[coltyp[j]]++;
              int psm[4];
              psm[0] = 0; psm[1] = ct[0]; psm[2] = ct[0]+ct[1]; psm[3] = ct[0]+ct[1]+ct[2];
              for (int j = 0; j < nm; j++) {
                int js = indxp[j], c4 = coltyp[js];
                indx[psm[c4]] = js; indxc[psm[c4]] = j; psm[c4]++;
              }
              icom[1] = k; icom[2] = ct[0]; icom[3] = ct[1]; icom[4] = ct[2]; icom[5] = ct[3];
            }
            icom[6] = (nrot <= CMDMAX) ? nrot : CMDMAX;
          }
          __syncthreads();
          {
            int nrot = icom[6];
            for (int base = 0; base < nrot; base += SCHUNK) {
              int cnt = nrot - base; if (cnt > SCHUNK) cnt = SCHUNK;
              for (int q = tid; q < cnt; q += NT) scmd[q] = cbuf[base+q];
              __syncthreads();
              for (int r = tid; r < nm; r += NT) {
#pragma unroll 2
                for (int q = 0; q < cnt; q++) {
                  Cmd cm = scmd[q];
                  double x = qb[(size_t)cm.a*ldn + r], y = qb[(size_t)cm.b*ldn + r];
                  qb[(size_t)cm.a*ldn + r] = cm.c*x + cm.s*y;
                  qb[(size_t)cm.b*ldn + r] = cm.c*y - cm.s*x;
                }
              }
              __syncthreads();
            }
          }
          int K = icom[1];
          if (K == 0) {
            for (int fl = tid; fl < nm*nm; fl += NT) {
              int jj2 = fl/nm, r = fl%nm;
              q2[(size_t)jj2*nm + r] = qb[(size_t)indx[jj2]*ldn + r];
            }
            __syncthreads();
            for (int fl = tid; fl < nm*nm; fl += NT) {
              int jj2 = fl/nm, r = fl%nm;
              qb[(size_t)jj2*ldn + r] = q2[(size_t)jj2*nm + r];
            }
            for (int i = tid; i < nm; i += NT) dm[i] = sdl[i];
            for (int i = tid; i < nm; i += NT) ixq[i] = i;
            __syncthreads();
          } else {
            int ct0 = icom[2], ct1 = icom[3], ct2 = icom[4];
            int n2c = nm - n1;
            int base2 = (ct0+ct1)*n1;
            int base4 = base2 + (ct1+ct2)*n2c;
            for (int i = tid; i < nm; i += NT) {
              int js = indx[i];
              const double* col = qb + (size_t)js*ldn;
              if (i < ct0) {
                double* dst = q2 + (size_t)i*n1;
#pragma unroll 4
                for (int r = 0; r < n1; r++) dst[r] = col[r];
              } else if (i < ct0+ct1) {
                double* d1 = q2 + (size_t)i*n1;
#pragma unroll 4
                for (int r = 0; r < n1; r++) d1[r] = col[r];
                double* d2 = q2 + base2 + (size_t)(i-ct0)*n2c;
#pragma unroll 4
                for (int r = 0; r < n2c; r++) d2[r] = col[n1+r];
              } else if (i < K) {
                double* d2 = q2 + base2 + (size_t)(i-ct0)*n2c;
#pragma unroll 4
                for (int r = 0; r < n2c; r++) d2[r] = col[n1+r];
              } else {
                double* d4 = q2 + base4 + (size_t)(i-K)*nm;
#pragma unroll 4
                for (int r = 0; r < nm; r++) d4[r] = col[r];
              }
              szv[i] = dm[js];
            }
            __syncthreads();
            for (int fl = tid; fl < (nm-K)*nm; fl += NT) {
              int jj2 = fl/nm, r = fl%nm;
              qb[(size_t)(K+jj2)*ldn + r] = q2[base4 + (size_t)jj2*nm + r];
            }
            for (int i = K+tid; i < nm; i += NT) dm[i] = szv[i];
            __syncthreads();
            double rho = dcom[0];
            for (int j = tid; j < K; j += NT) {
              double lam;
              my_laed4(K, j, sdl, sw, rho, qb + (size_t)j*ldn, &lam);
              dm[j] = lam;
            }
            __syncthreads();
            if (K == 2) {
              if (tid == 0) {
                for (int j = 0; j < 2; j++) {
                  double a0 = qb[(size_t)j*ldn + 0], a1 = qb[(size_t)j*ldn + 1];
                  qb[(size_t)j*ldn + 0] = (indxc[0] == 0) ? a0 : a1;
                  qb[(size_t)j*ldn + 1] = (indxc[1] == 0) ? a0 : a1;
                }
              }
              __syncthreads();
            } else if (K >= 3) {
              for (int i = tid; i < K; i += NT) szv[i] = sw[i];
              __syncthreads();
              for (int i = tid; i < K; i += NT) {
                double prod = qb[(size_t)i*ldn + i];
#pragma unroll 4
                for (int j = 0; j < K; j++) {
                  if (j == i) continue;
                  prod *= qb[(size_t)j*ldn + i] / (sdl[i]-sdl[j]);
                }
                sw[i] = d_sign(sqrt(fmax(-prod, 0.0)), szv[i]);
              }
              __syncthreads();
              for (int j = tid; j < K; j += NT) {
                double nrm = 0.0;
#pragma unroll 4
                for (int i = 0; i < K; i++) {
                  double v = sw[i]/qb[(size_t)j*ldn + i];
                  sbuf[(size_t)j*K + i] = v;
                  nrm += v*v;
                }
                ss2[j] = sqrt(nrm);
              }
              __syncthreads();
              for (int fl = tid; fl < K*K; fl += NT) {
                int jj2 = fl/K, i = fl%K;
                qb[(size_t)jj2*ldn + i] = sbuf[(size_t)jj2*K + indxc[i]] / ss2[jj2];
              }
              __syncthreads();
            }
            int n12 = ct0+ct1, n23 = ct1+ct2;
            for (int fl = tid; fl < n23*K; fl += NT) {
              int jj2 = fl/n23, i = fl%n23;
              sbuf[(size_t)jj2*n23 + i] = qb[(size_t)jj2*ldn + ct0 + i];
            }
            __syncthreads();
            for (int fl = tid; fl < n2c*K; fl += NT) {
              int jj2 = fl/n2c, r = fl%n2c;
              const double* srow = sbuf + (size_t)jj2*n23;
              double acc = 0.0;
              int l = 0;
              int rem = n23 & 7;
              for (; l < rem; l++) acc += q2[base2 + (size_t)l*n2c + r] * srow[l];
              for (; l < n23; l += 8) {
                double x0 = q2[base2 + (size_t)(l+0)*n2c + r];
                double x1 = q2[base2 + (size_t)(l+1)*n2c + r];
                double x2 = q2[base2 + (size_t)(l+2)*n2c + r];
                double x3 = q2[base2 + (size_t)(l+3)*n2c + r];
                double x4 = q2[base2 + (size_t)(l+4)*n2c + r];
                double x5 = q2[base2 + (size_t)(l+5)*n2c + r];
                double x6 = q2[base2 + (size_t)(l+6)*n2c + r];
                double x7 = q2[base2 + (size_t)(l+7)*n2c + r];
                double y0 = srow[l+0], y1 = srow[l+1], y2 = srow[l+2], y3 = srow[l+3];
                double y4 = srow[l+4], y5 = srow[l+5], y6 = srow[l+6], y7 = srow[l+7];
                acc += x0*y0; acc += x1*y1; acc += x2*y2; acc += x3*y3;
                acc += x4*y4; acc += x5*y5; acc += x6*y6; acc += x7*y7;
              }
              qb[(size_t)jj2*ldn + n1 + r] = acc;
            }
            __syncthreads();
            for (int fl = tid; fl < n12*K; fl += NT) {
              int jj2 = fl/n12, i = fl%n12;
              sbuf[(size_t)jj2*n12 + i] = qb[(size_t)jj2*ldn + i];
            }
            __syncthreads();
            for (int fl = tid; fl < n1*K; fl += NT) {
              int jj2 = fl/n1, r = fl%n1;
              const double* srow = sbuf + (size_t)jj2*n12;
              double acc = 0.0;
              int l = 0;
              int rem = n12 & 7;
              for (; l < rem; l++) acc += q2[(size_t)l*n1 + r] * srow[l];
              for (; l < n12; l += 8) {
                double x0 = q2[(size_t)(l+0)*n1 + r];
                double x1 = q2[(size_t)(l+1)*n1 + r];
                double x2 = q2[(size_t)(l+2)*n1 + r];
                double x3 = q2[(size_t)(l+3)*n1 + r];
                double x4 = q2[(size_t)(l+4)*n1 + r];
                double x5 = q2[(size_t)(l+5)*n1 + r];
                double x6 = q2[(size_t)(l+6)*n1 + r];
                double x7 = q2[(size_t)(l+7)*n1 + r];
                double y0 = srow[l+0], y1 = srow[l+1], y2 = srow[l+2], y3 = srow[l+3];
                double y4 = srow[l+4], y5 = srow[l+5], y6 = srow[l+6], y7 = srow[l+7];
                acc += x0*y0; acc += x1*y1; acc += x2*y2; acc += x3*y3;
                acc += x4*y4; acc += x5*y5; acc += x6*y6; acc += x7*y7;
              }
              qb[(size_t)jj2*ldn + r] = acc;
            }
            __syncthreads();
            if (tid == 0) dlamrg(K, nm-K, dm, 1, -1, ixq);
            __syncthreads();
          }
        }
        if (tid == 0) iw[i2/2] = iw[i2+1];
        __syncthreads();
      }
      sp /= 2;
    }
    {
      int msz2 = finish - startb + 1;
      for (int i = tid; i < msz2; i += NT) dtmp[i] = sd[startb + indxq[startb+i]];
      for (int fl = tid; fl < msz2*msz2; fl += NT) {
        int i = fl/msz2, r = fl%msz2;
        qtmp[(size_t)i*msz2 + r] = Z[(size_t)(startb + indxq[startb+i])*n + startb + r];
      }
      __syncthreads();
      for (int i = tid; i < msz2; i += NT) sd[startb+i] = dtmp[i];
      for (int fl = tid; fl < msz2*msz2; fl += NT) {
        int i = fl/msz2, r = fl%msz2;
        Z[(size_t)(startb+i)*n + startb + r] = qtmp[(size_t)i*msz2 + r];
      }
      __syncthreads();
      if (tid == 0) {
        double onrm = dcom[7];
        for (int i = startb; i <= finish; i++) sd[i] *= onrm;
      }
      __syncthreads();
    }
    startb = finish + 1;
  }
  if (nblk > 1) {
    for (int ii = 1; ii <= n-1; ii++) {
      if (tid == 0) {
        int i = ii-1, kk = i; double p = sd[i];
        for (int j = ii; j <= n-1; j++) if (sd[j] < p) { kk = j; p = sd[j]; }
        icom[7] = kk;
        if (kk != i) { sd[kk] = sd[i]; sd[i] = p; }
      }
      __syncthreads();
      int kk = icom[7], i = ii-1;
      if (kk != i) {
        for (int r = tid; r < n; r += NT) {
          double t = Z[(size_t)i*n + r];
          Z[(size_t)i*n + r] = Z[(size_t)kk*n + r];
          Z[(size_t)kk*n + r] = t;
        }
      }
      __syncthreads();
    }
  }
}

// ============================ split-STEDC schedule types ============================
struct MTask { int startb, submat, matsiz, msd2, scrOff, cmdSlot; };
struct Sched {
  int mcount[MLEV];
  MTask mt[MLEV][MAXTASK];
  int npb; int pad;
  int pb_start[64]; int pb_msz[64]; int pb_isDC[64];
  double pb_onrm[64];
};

// ============================ k_stedc_pre: partition + LAED0 + leaves + schedule ============================
template<int NT>
__global__ __launch_bounds__(NT) void k_stedc_pre(int n, double* Z, double* gwrk,
                                                  double* gSd, double* gSe, int* gIxq,
                                                  Sched* sc){
  __shared__ double sd[384], se[384];
  __shared__ int ixq[384];
  __shared__ int iw[40], icom[16], icom2[16];
  __shared__ Cmd scmd[SCHUNK];
  const int tid = threadIdx.x;
  for (int i = tid; i < n; i += NT){ sd[i] = gSd[i]; ixq[i] = 0; }
  for (int i = tid; i < n-1; i += NT) se[i] = gSe[i];
  for (size_t x = tid; x < (size_t)n*n; x += NT) Z[x] = ((x % (size_t)(n+1)) == 0) ? 1.0 : 0.0;
  if (tid == 0){ for (int L = 0; L < MLEV; L++) sc->mcount[L] = 0; sc->npb = 0; }
  __syncthreads();
  long offL[MLEV] = {0,0,0,0};   // thread0-only bookkeeping
  int startb = 0;
  while (startb < n) {
    if (tid == 0) {
      int finish = startb;
      while (finish < n-1) {
        double tiny = D_EPS*sqrt(fabs(sd[finish]))*sqrt(fabs(sd[finish+1]));
        if (fabs(se[finish]) > tiny) finish++; else break;
      }
      icom[9] = finish;
      int p = sc->npb;
      int msz = finish - startb + 1;
      sc->pb_start[p] = startb; sc->pb_msz[p] = msz;
      sc->pb_isDC[p] = (msz > SMLSIZ) ? 1 : 0;
      sc->pb_onrm[p] = 1.0;
      sc->npb = p+1;
    }
    __syncthreads();
    int finish = icom[9];
    int msz = finish - startb + 1;
    if (msz == 1) { startb = finish+1; __syncthreads(); continue; }
    if (msz <= SMLSIZ) {
      dev_steqr<NT>(msz, sd+startb, se+startb, Z + (size_t)startb*n + startb, n,
                    (Cmd*)gwrk, icom, scmd);
      startb = finish+1; __syncthreads(); continue;
    }
    if (tid == 0) {
      double onrm = 0.0;
      for (int i = startb; i <= finish; i++) onrm = fmax(onrm, fabs(sd[i]));
      for (int i = startb; i <  finish; i++) onrm = fmax(onrm, fabs(se[i]));
      if (onrm == 0.0) onrm = 1.0;
      sc->pb_onrm[sc->npb - 1] = onrm;
      double inv = 1.0/onrm;
      for (int i = startb; i <= finish; i++) sd[i] *= inv;
      for (int i = startb; i <  finish; i++) se[i] *= inv;
      iw[0] = msz; int sp0 = 1;
      while (iw[sp0-1] > SMLSIZ) {
        for (int j = sp0-1; j >= 0; j--) { iw[2*j+1] = (iw[j]+1)/2; iw[2*j] = iw[j]/2; }
        sp0 *= 2;
      }
      for (int j = 1; j < sp0; j++) iw[j] += iw[j-1];
      icom[8] = sp0;
      for (int i = 0; i < sp0-1; i++) {
        int bb = startb + iw[i] - 1;
        sd[bb]   -= fabs(se[bb]);
        sd[bb+1] -= fabs(se[bb]);
      }
    }
    __syncthreads();
    int sp = icom[8];
    {
      const int wid = tid >> 6, lane = tid & 63;
      const int nwaves = NT/64;
      Cmd* cb0 = (Cmd*)gwrk;
      for (int li = wid; li < sp; li += nwaves) {
        if (lane == 0) {
          int submat = (li == 0) ? 0 : iw[li-1];
          int matsiz = iw[li] - submat;
          icom2[li] = (matsiz > 1)
            ? steqr_scan(matsiz, sd+startb+submat, se+startb+submat, cb0 + (size_t)li*CMDMAX, CMDMAX)
            : 0;
        }
      }
      __syncthreads();
      for (int li = wid; li < sp; li += nwaves) {
        int submat = (li == 0) ? 0 : iw[li-1];
        int matsiz = iw[li] - submat;
        int nc = icom2[li];
        double* zb = Z + (size_t)(startb+submat)*n + (startb+submat);
        Cmd* cb = cb0 + (size_t)li*CMDMAX;
        if (lane < matsiz) {
#pragma unroll 2
          for (int q = 0; q < nc; q++) apply_cmd(cb[q], zb, n, lane);
        }
      }
      __syncthreads();
      for (int x = tid; x < msz; x += NT) {
        int sub = 0;
        for (int t = 0; t < sp; t++) { if (x < iw[t]) { sub = (t == 0) ? 0 : iw[t-1]; break; } }
        ixq[startb + x] = x - sub;
      }
      __syncthreads();
    }
    if (tid == 0) {
      int lvl = 0, spp = sp;
      while (spp > 1 && lvl < MLEV) {
        for (int i2 = 0; i2 <= spp-2; i2 += 2) {
          int submat, matsiz, msd2;
          if (i2 == 0) { submat = 0; matsiz = iw[1]; msd2 = iw[0]; }
          else { submat = iw[i2-1]; matsiz = iw[i2+1]-iw[i2-1]; msd2 = matsiz/2; }
          int slot = sc->mcount[lvl];
          if (slot < MAXTASK) {
            MTask tk; tk.startb = startb; tk.submat = submat; tk.matsiz = matsiz;
            tk.msd2 = msd2; tk.scrOff = (int)offL[lvl]; tk.cmdSlot = slot;
            sc->mt[lvl][slot] = tk;
            sc->mcount[lvl] = slot+1;
            offL[lvl] += 3L*matsiz*matsiz;
          }
          iw[i2/2] = iw[i2+1];
        }
        spp /= 2; lvl++;
      }
    }
    __syncthreads();
    startb = finish + 1;
  }
  __syncthreads();
  for (int i = tid; i < n; i += NT) { gSd[i] = sd[i]; gIxq[i] = ixq[i]; }
  for (int i = tid; i < n-1; i += NT) gSe[i] = se[i];
}

// ============================ k_stedc_merge: one block per merge task ============================
template<int NT>
__global__ __launch_bounds__(NT) void k_stedc_merge(int n, int level, double* Z,
                                                    double* gwrk, double* gSd,
                                                    const double* gSe, int* gIxq,
                                                    Sched* sc){
  __shared__ double dml[384], sdl[384], sw[384], szv[384], ss2[384];
  __shared__ double dcom[4];
  __shared__ int ixql[384], indx[384], indxc[384], indxp[384], coltyp[384];
  __shared__ int icom[8];
  __shared__ Cmd scmd[SCHUNK];
  const int tid = threadIdx.x;
  if ((int)blockIdx.x >= sc->mcount[level]) return;
  MTask tk = sc->mt[level][blockIdx.x];
  const int nm = tk.matsiz, n1 = tk.msd2, ldn = n;
  const int base0 = tk.startb + tk.submat;
  double* qb = Z + (size_t)base0*n + base0;
  double* q2 = gwrk + tk.scrOff;
  double* sbuf = q2 + 2*(size_t)nm*nm;
  Cmd* cbuf = (Cmd*)(gwrk + CMDTOP_DBL) + (size_t)tk.cmdSlot*MERGE_CMD;
  double rho_in = gSe[base0 + n1 - 1];

  for (int i = tid; i < nm; i += NT) { dml[i] = gSd[base0+i]; ixql[i] = gIxq[base0+i]; }
  __syncthreads();
  for (int i = tid; i < n1; i += NT)      szv[i] = qb[(size_t)i*ldn + (n1-1)];
  for (int i = n1+tid; i < nm; i += NT)   szv[i] = qb[(size_t)i*ldn + n1];
  __syncthreads();
  // LAED2 scan (thread 0)
  if (tid == 0) {
    int nrot = 0;
    const int n2_ = nm - n1;
    double rho = rho_in;
    if (rho < 0.0) for (int i = n1; i < nm; i++) szv[i] = -szv[i];
    double tsc = 1.0/sqrt(2.0);
    for (int i = 0; i < nm; i++) szv[i] *= tsc;
    rho = fabs(2.0*rho);
    dcom[0] = rho;
    for (int i = n1; i < nm; i++) ixql[i] += n1;
    for (int i = 0; i < nm; i++) sdl[i] = dml[ixql[i]];
    dlamrg(n1, n2_, sdl, 1, 1, indxc);
    for (int i = 0; i < nm; i++) indx[i] = ixql[indxc[i]];
    int imax = 0, jmax = 0;
    for (int i = 1; i < nm; i++) {
      if (fabs(szv[i]) > fabs(szv[imax])) imax = i;
      if (fabs(dml[i]) > fabs(dml[jmax])) jmax = i;
    }
    double tol = 8.0*D_EPS*fmax(fabs(dml[jmax]), fabs(szv[imax]));
    if (rho*fabs(szv[imax]) <= tol) {
      icom[1] = 0;
      for (int j = 0; j < nm; j++) sdl[j] = dml[indx[j]];
    } else {
      for (int i = 0; i < n1; i++) coltyp[i] = 0;
      for (int i = n1; i < nm; i++) coltyp[i] = 2;
      int k = 0, k2 = nm;
      int pj = 0, jj = 0;
      bool haveP = false;
      for (jj = 0; jj < nm; jj++) {
        int nj = indx[jj];
        if (rho*fabs(szv[nj]) <= tol) { k2--; coltyp[nj] = 3; indxp[k2] = nj; }
        else { pj = nj; haveP = true; jj++; break; }
      }
      if (haveP) {
        while (1) {
          if (jj > nm-1) break;
          int nj = indx[jj];
          if (rho*fabs(szv[nj]) <= tol) { k2--; coltyp[nj] = 3; indxp[k2] = nj; }
          else {
            double s_ = szv[pj], c_ = szv[nj];
            double tau = dlapy2(c_, s_);
            double tdf = dml[nj] - dml[pj];
            c_ = c_/tau; s_ = -s_/tau;
            if (fabs(tdf*c_*s_) <= tol) {
              szv[nj] = tau; szv[pj] = 0.0;
              if (coltyp[nj] != coltyp[pj]) coltyp[nj] = 1;
              coltyp[pj] = 3;
              if (nrot < MERGE_CMD) { cbuf[nrot].c = c_; cbuf[nrot].s = s_; cbuf[nrot].a = pj; cbuf[nrot].b = nj; }
              nrot++;
              double t2 = dml[pj]*c_*c_ + dml[nj]*s_*s_;
              dml[nj] = dml[pj]*s_*s_ + dml[nj]*c_*c_;
              dml[pj] = t2;
              k2--;
              int i1 = 1;
              while (1) {
                if (k2 + i1 <= nm-1) {
                  if (dml[pj] < dml[indxp[k2+i1]]) {
                    indxp[k2+i1-1] = indxp[k2+i1];
                    indxp[k2+i1] = pj;
                    i1++;
                  } else { indxp[k2+i1-1] = pj; break; }
                } else { indxp[k2+i1-1] = pj; break; }
              }
              pj = nj;
            } else {
              k++; sdl[k-1] = dml[pj]; sw[k-1] = szv[pj]; indxp[k-1] = pj; pj = nj;
            }
          }
          jj++;
        }
        k++; sdl[k-1] = dml[pj]; sw[k-1] = szv[pj]; indxp[k-1] = pj;
      }
      int ct[4] = {0,0,0,0};
      for (int j = 0; j < nm; j++) ct[coltyp[j]]++;
      int psm[4];
      psm[0] = 0; psm[1] = ct[0]; psm[2] = ct[0]+ct[1]; psm[3] = ct[0]+ct[1]+ct[2];
      for (int j = 0; j < nm; j++) {
        int js = indxp[j], c4 = coltyp[js];
        indx[psm[c4]] = js; indxc[psm[c4]] = j; psm[c4]++;
      }
      icom[1] = k; icom[2] = ct[0]; icom[3] = ct[1]; icom[4] = ct[2]; icom[5] = ct[3];
    }
    icom[6] = (nrot <= MERGE_CMD) ? nrot : MERGE_CMD;
  }
  __syncthreads();
  // parallel replay of deflation Givens rotations
  {
    int nrot = icom[6];
    for (int base = 0; base < nrot; base += SCHUNK) {
      int cnt = nrot - base; if (cnt > SCHUNK) cnt = SCHUNK;
      for (int q = tid; q < cnt; q += NT) scmd[q] = cbuf[base+q];
      __syncthreads();
      for (int r = tid; r < nm; r += NT) {
#pragma unroll 2
        for (int q = 0; q < cnt; q++) {
          Cmd cm = scmd[q];
          double x = qb[(size_t)cm.a*ldn + r], y = qb[(size_t)cm.b*ldn + r];
          qb[(size_t)cm.a*ldn + r] = cm.c*x + cm.s*y;
          qb[(size_t)cm.b*ldn + r] = cm.c*y - cm.s*x;
        }
      }
      __syncthreads();
    }
  }
  int K = icom[1];
  if (K == 0) {
    for (int fl = tid; fl < nm*nm; fl += NT) {
      int jj2 = fl/nm, r = fl%nm;
      q2[(size_t)jj2*nm + r] = qb[(size_t)indx[jj2]*ldn + r];
    }
    __syncthreads();
    for (int fl = tid; fl < nm*nm; fl += NT) {
      int jj2 = fl/nm, r = fl%nm;
      qb[(size_t)jj2*ldn + r] = q2[(size_t)jj2*nm + r];
    }
    for (int i = tid; i < nm; i += NT) dml[i] = sdl[i];
    for (int i = tid; i < nm; i += NT) ixql[i] = i;
    __syncthreads();
  } else {
    int ct0 = icom[2], ct1 = icom[3], ct2 = icom[4];
    int n2c = nm - n1;
    int base2 = (ct0+ct1)*n1;
    int base4 = base2 + (ct1+ct2)*n2c;
    for (int i = tid; i < nm; i += NT) {
      int js = indx[i];
      const double* col = qb + (size_t)js*ldn;
      if (i < ct0) {
        double* dst = q2 + (size_t)i*n1;
#pragma unroll 4
        for (int r = 0; r < n1; r++) dst[r] = col[r];
      } else if (i < ct0+ct1) {
        double* d1 = q2 + (size_t)i*n1;
#pragma unroll 4
        for (int r = 0; r < n1; r++) d1[r] = col[r];
        double* d2 = q2 + base2 + (size_t)(i-ct0)*n2c;
#pragma unroll 4
        for (int r = 0; r < n2c; r++) d2[r] = col[n1+r];
      } else if (i < K) {
        double* d2 = q2 + base2 + (size_t)(i-ct0)*n2c;
#pragma unroll 4
        for (int r = 0; r < n2c; r++) d2[r] = col[n1+r];
      } else {
        double* d4 = q2 + base4 + (size_t)(i-K)*nm;
#pragma unroll 4
        for (int r = 0; r < nm; r++) d4[r] = col[r];
      }
      szv[i] = dml[js];
    }
    __syncthreads();
    for (int fl = tid; fl < (nm-K)*nm; fl += NT) {
      int jj2 = fl/nm, r = fl%nm;
      qb[(size_t)(K+jj2)*ldn + r] = q2[base4 + (size_t)jj2*nm + r];
    }
    for (int i = K+tid; i < nm; i += NT) dml[i] = szv[i];
    __syncthreads();
    // LAED3
    double rho = dcom[0];
    for (int j = tid; j < K; j += NT) {
      double lam;
      my_laed4(K, j, sdl, sw, rho, qb + (size_t)j*ldn, &lam);
      dml[j] = lam;
    }
    __syncthreads();
    if (K == 2) {
      if (tid == 0) {
        for (int j = 0; j < 2; j++) {
          double a0 = qb[(size_t)j*ldn + 0], a1 = qb[(size_t)j*ldn + 1];
          qb[(size_t)j*ldn + 0] = (indxc[0] == 0) ? a0 : a1;
          qb[(size_t)j*ldn + 1] = (indxc[1] == 0) ? a0 : a1;
        }
      }
      __syncthreads();
    } else if (K >= 3) {
      for (int i = tid; i < K; i += NT) szv[i] = sw[i];
      __syncthreads();
      for (int i = tid; i < K; i += NT) {
        double prod = qb[(size_t)i*ldn + i];
#pragma unroll 4
        for (int j = 0; j < K; j++) {
          if (j == i) continue;
          prod *= qb[(size_t)j*ldn + i] / (sdl[i]-sdl[j]);
        }
        sw[i] = d_sign(sqrt(fmax(-prod, 0.0)), szv[i]);
      }
      __syncthreads();
      for (int j = tid; j < K; j += NT) {
        double nrm = 0.0;
#pragma unroll 4
        for (int i = 0; i < K; i++) {
          double v = sw[i]/qb[(size_t)j*ldn + i];
          sbuf[(size_t)j*K + i] = v;
          nrm += v*v;
        }
        ss2[j] = sqrt(nrm);
      }
      __syncthreads();
      for (int fl = tid; fl < K*K; fl += NT) {
        int jj2 = fl/K, i = fl%K;
        qb[(size_t)jj2*ldn + i] = sbuf[(size_t)jj2*K + indxc[i]] / ss2[jj2];
      }
      __syncthreads();
    }
    // assembly
    int n12 = ct0+ct1, n23 = ct1+ct2;
    for (int fl = tid; fl < n23*K; fl += NT) {
      int jj2 = fl/n23, i = fl%n23;
      sbuf[(size_t)jj2*n23 + i] = qb[(size_t)jj2*ldn + ct0 + i];
    }
    __syncthreads();
    for (int fl = tid; fl < n2c*K; fl += NT) {
      int jj2 = fl/n2c, r = fl%n2c;
      const double* srow = sbuf + (size_t)jj2*n23;
      double acc = 0.0;
      int l = 0;
      int rem = n23 & 7;
      for (; l < rem; l++) acc += q2[base2 + (size_t)l*n2c + r] * srow[l];
      for (; l < n23; l += 8) {
        double x0 = q2[base2 + (size_t)(l+0)*n2c + r];
        double x1 = q2[base2 + (size_t)(l+1)*n2c + r];
        double x2 = q2[base2 + (size_t)(l+2)*n2c + r];
        double x3 = q2[base2 + (size_t)(l+3)*n2c + r];
        double x4 = q2[base2 + (size_t)(l+4)*n2c + r];
        double x5 = q2[base2 + (size_t)(l+5)*n2c + r];
        double x6 = q2[base2 + (size_t)(l+6)*n2c + r];
        double x7 = q2[base2 + (size_t)(l+7)*n2c + r];
        double y0 = srow[l+0], y1 = srow[l+1], y2 = srow[l+2], y3 = srow[l+3];
        double y4 = srow[l+4], y5 = srow[l+5], y6 = srow[l+6], y7 = srow[l+7];
        acc += x0*y0; acc += x1*y1; acc += x2*y2; acc += x3*y3;
        acc += x4*y4; acc += x5*y5; acc += x6*y6; acc += x7*y7;
      }
      qb[(size_t)jj2*ldn + n1 + r] = acc;
    }
    __syncthreads();
    for (int fl = tid; fl < n12*K; fl += NT) {
      int jj2 = fl/n12, i = fl%n12;
      sbuf[(size_t)jj2*n12 + i] = qb[(size_t)jj2*ldn + i];
    }
    __syncthreads();
    for (int fl = tid; fl < n1*K; fl += NT) {
      int jj2 = fl/n1, r = fl%n1;
      const double* srow = sbuf + (size_t)jj2*n12;
      double acc = 0.0;
      int l = 0;
      int rem = n12 & 7;
      for (; l < rem; l++) acc += q2[(size_t)l*n1 + r] * srow[l];
      for (; l < n12; l += 8) {
        double x0 = q2[(size_t)(l+0)*n1 + r];
        double x1 = q2[(size_t)(l+1)*n1 + r];
        double x2 = q2[(size_t)(l+2)*n1 + r];
        double x3 = q2[(size_t)(l+3)*n1 + r];
        double x4 = q2[(size_t)(l+4)*n1 + r];
        double x5 = q2[(size_t)(l+5)*n1 + r];
        double x6 = q2[(size_t)(l+6)*n1 + r];
        double x7 = q2[(size_t)(l+7)*n1 + r];
        double y0 = srow[l+0], y1 = srow[l+1], y2 = srow[l+2], y3 = srow[l+3];
        double y4 = srow[l+4], y5 = srow[l+5], y6 = srow[l+6], y7 = srow[l+7];
        acc += x0*y0; acc += x1*y1; acc += x2*y2; acc += x3*y3;
        acc += x4*y4; acc += x5*y5; acc += x6*y6; acc += x7*y7;
      }
      qb[(size_t)jj2*ldn + r] = acc;
    }
    __syncthreads();
    if (tid == 0) dlamrg(K, nm-K, dml, 1, -1, ixql);
    __syncthreads();
  }
  for (int i = tid; i < nm; i += NT) { gSd[base0+i] = dml[i]; gIxq[base0+i] = ixql[i]; }
}

// ============================ k_stedc_fin: reorder + rescale + rare sort ============================
template<int NT>
__global__ __launch_bounds__(NT) void k_stedc_fin(int n, double* Z, double* Dout,
                                                  double* gwrk, double* gSd, int* gIxq,
                                                  Sched* sc){
  __shared__ int icom[4];
  const int tid = threadIdx.x;
  double* qtmp = gwrk;
  double* dtmp = gwrk + (size_t)n*n;
  int npb = sc->npb;
  for (int p = 0; p < npb; p++) {
    int s = sc->pb_start[p], msz = sc->pb_msz[p];
    if (sc->pb_isDC[p]) {
      double onrm = sc->pb_onrm[p];
      for (int i = tid; i < msz; i += NT) dtmp[i] = gSd[s + gIxq[s+i]];
      for (int fl = tid; fl < msz*msz; fl += NT) {
        int i = fl/msz, r = fl%msz;
        qtmp[(size_t)i*msz + r] = Z[(size_t)(s + gIxq[s+i])*n + s + r];
      }
      __syncthreads();
      for (int i = tid; i < msz; i += NT) gSd[s+i] = dtmp[i]*onrm;
      for (int fl = tid; fl < msz*msz; fl += NT) {
        int i = fl/msz, r = fl%msz;
        Z[(size_t)(s+i)*n + s + r] = qtmp[(size_t)i*msz + r];
      }
      __syncthreads();
    }
  }
  if (npb > 1) {
    for (int ii = 1; ii <= n-1; ii++) {
      if (tid == 0) {
        int i = ii-1, kk = i; double p = gSd[i];
        for (int j = ii; j <= n-1; j++) if (gSd[j] < p) { kk = j; p = gSd[j]; }
        icom[0] = kk;
        if (kk != i) { gSd[kk] = gSd[i]; gSd[i] = p; }
      }
      __syncthreads();
      int kk = icom[0], i = ii-1;
      if (kk != i) {
        for (int r = tid; r < n; r += NT) {
          double t = Z[(size_t)i*n + r];
          Z[(size_t)i*n + r] = Z[(size_t)kk*n + r];
          Z[(size_t)kk*n + r] = t;
        }
      }
      __syncthreads();
    }
  }
  for (int i = tid; i < n; i += NT) Dout[i] = gSd[i];
}

// ============================ eigh kernels ============================
template<int NT, int MAXN>
__global__ __launch_bounds__(NT) void k_eigh_small(int n, const double* __restrict__ Ain,
                                                   double* __restrict__ Zout,
                                                   double* __restrict__ Dout,
                                                   double* gwrk){
  __shared__ double sd[MAXN], se[MAXN], stau[MAXN], sdl[MAXN], sw[MAXN], szv[MAXN], ss2[MAXN];
  __shared__ double red[NT], dcom[8];
  __shared__ int indx[MAXN], indxc[MAXN], indxp[MAXN], coltyp[MAXN], indxq[MAXN];
  __shared__ int iw[40], icom[16], icom2[16];
  __shared__ Cmd scmd[SCHUNK];
  extern __shared__ double dyn[];
  double* A = dyn;
  double* Z = dyn + n*n;
  const int tid = threadIdx.x;

  for (int x = tid; x < n*n; x += NT) A[x] = Ain[x];
  __syncthreads();

  sytd2_dev<NT>(n, A, sd, se, stau, szv, red, dcom);

  for (int x = tid; x < n*n; x += NT) Z[x] = ((x % (n+1)) == 0) ? 1.0 : 0.0;
  __syncthreads();

  stedc_dev<NT>(n, Z, gwrk, sd, se, sdl, sw, szv, ss2, dcom,
                indx, indxc, indxp, coltyp, indxq, iw, icom, icom2, scmd);

  __syncthreads();
  for (int j = tid; j < n; j += NT) {
    for (int ii = n-2; ii >= 0; ii--) {
      double tau_i = stau[ii];
      if (tau_i == 0.0) continue;
      double w = Z[(size_t)j*n + ii + 1];
#pragma unroll 4
      for (int r = ii+2; r < n; r++) w += A[(size_t)ii*n + r] * Z[(size_t)j*n + r];
      w *= tau_i;
      Z[(size_t)j*n + ii + 1] -= w;
#pragma unroll 4
      for (int r = ii+2; r < n; r++) Z[(size_t)j*n + r] -= w * A[(size_t)ii*n + r];
    }
  }
  __syncthreads();
  for (int x = tid; x < n*n; x += NT) Zout[x] = Z[x];
  for (int i = tid; i < n; i += NT) Dout[i] = sd[i];
}

template<int NT>
__global__ __launch_bounds__(NT) void k_sytd2_big(int n, double* A,
                                                  double* gsd, double* gse, double* gtau){
  __shared__ double sd[384], se[384], stau[384], vv[384], ww[384];
  __shared__ double red[16], dcom[8];
  const int tid = threadIdx.x;
  sytd2_big<NT>(n, A, sd, se, stau, vv, ww, red, dcom);
  for (int i = tid; i < n; i += NT) {
    gsd[i] = sd[i];
    gtau[i] = stau[i];
    if (i < n-1) gse[i] = se[i];
  }
}

#define OB_COLS 8
__global__ __launch_bounds__(256) void k_ormtr_big(int n, const double* __restrict__ A,
                                                   double* __restrict__ Z,
                                                   const double* __restrict__ tau,
                                                   int col0base){
  __shared__ double zc[OB_COLS][384];
  __shared__ double vsh[384];
  int col0 = col0base + blockIdx.x * OB_COLS;
  int tid = threadIdx.x;
  int c = tid >> 5;
  int l = tid & 31;
  for (int x = tid; x < OB_COLS*n; x += 256) {
    int cc = x / n, r = x % n;
    if (col0+cc < n) zc[cc][r] = Z[(size_t)(col0+cc)*n + r];
  }
  __syncthreads();
  for (int ii = n-2; ii >= 0; ii--) {
    double ti = tau[ii];
    if (ti != 0.0) {
      for (int r = ii+2+tid; r < n; r += 256) vsh[r] = A[(size_t)ii*n + r];
      __syncthreads();
      double p = (l == 0) ? zc[c][ii+1] : 0.0;
#pragma unroll 4
      for (int r = ii+2+l; r < n; r += 32) p += vsh[r]*zc[c][r];
      for (int off = 16; off > 0; off >>= 1) p += __shfl_down(p, off, 32);
      double w = __shfl(p, 0, 32) * ti;
      if (l == 0) zc[c][ii+1] -= w;
#pragma unroll 4
      for (int r = ii+2+l; r < n; r += 32) zc[c][r] -= w*vsh[r];
      __syncthreads();
    }
  }
  for (int x = tid; x < OB_COLS*n; x += 256) {
    int cc = x / n, r = x % n;
    if (col0+cc < n) Z[(size_t)(col0+cc)*n + r] = zc[cc][r];
  }
}

// ============================ data kernels ============================
__global__ __launch_bounds__(TPB) void k_conv(const float* __restrict__ st,
                                              const float* __restrict__ cw,
                                              const float* __restrict__ cb,
                                              float* __restrict__ sv){
  int idx = blockIdx.x*TPB + threadIdx.x;
  if (idx >= 28311552) return;
  int w = idx % 24; int t = idx/24;
  int h = t % 384; t /= 384;
  int d = t % 96; int o = t/96;
  float acc = cb[o];
  for (int i = 0; i < 4; i++)
    for (int kh = 0; kh < 3; kh++)
      acc += st[(((size_t)i*96+d)*386 + h+kh)*24 + w] * cw[(o*4+i)*3 + kh];
  sv[idx] = fmaxf(acc, 0.0f);
}

__global__ __launch_bounds__(TPB) void k_g0p(const float* __restrict__ sv, double* parts){
  __shared__ float slab[32*25];
  int b = blockIdx.x;
  double acc[4]; int c1s[4], c2s[4];
#pragma unroll
  for (int k = 0; k < 4; k++) { int e = threadIdx.x + k*TPB; acc[k] = 0.0; c1s[k] = e/32; c2s[k] = e%32; }
  for (int q = 0; q < 128; q++) {
    int s = b*128 + q; int d = s/384, p = s%384;
    for (int l = threadIdx.x; l < 768; l += TPB) {
      int cc = l/24, w = l-cc*24;
      slab[cc*25+w] = sv[(((size_t)cc*96+d)*384+p)*24 + w];
    }
    __syncthreads();
#pragma unroll
    for (int k = 0; k < 4; k++) {
      double sacc = 0.0;
      const float* r1 = slab + c1s[k]*25;
      const float* r2 = slab + c2s[k]*25;
      for (int w = 0; w < 24; w++) sacc += (double)r1[w]*(double)r2[w];
      acc[k] += sacc;
    }
    __syncthreads();
  }
  for (int k = 0; k < 4; k++) parts[(size_t)b*1024 + threadIdx.x + k*TPB] = acc[k];
}
__global__ __launch_bounds__(TPB) void k_g1p(const float* __restrict__ sv, double* parts){
  __shared__ float slab[96*25];
  int c = blockIdx.x;
  double acc[36]; int d1s[36], d2s[36];
#pragma unroll
  for (int k = 0; k < 36; k++) { int e = threadIdx.x + k*TPB; acc[k] = 0.0; d1s[k] = e/96; d2s[k] = e%96; }
  for (int p = 0; p < 384; p++) {
    for (int l = threadIdx.x; l < 2304; l += TPB) {
      int d = l/24, w = l-d*24;
      slab[d*25+w] = sv[(((size_t)c*96+d)*384+p)*24 + w];
    }
    __syncthreads();
#pragma unroll
    for (int k = 0; k < 36; k++) {
      double sacc = 0.0;
      const float* r1 = slab + d1s[k]*25;
      const float* r2 = slab + d2s[k]*25;
      for (int w = 0; w < 24; w++) sacc += (double)r1[w]*(double)r2[w];
      acc[k] += sacc;
    }
    __syncthreads();
  }
  for (int k = 0; k < 36; k++) parts[(size_t)c*9216 + threadIdx.x + k*TPB] = acc[k];
}
#define G2_NKG 6
__global__ __launch_bounds__(TPB) void k_g2p(const float* __restrict__ sv, double* parts){
  __shared__ float aS[64*25], bS[64*25];
  int blk = blockIdx.x;
  int kg = blk/36, t2 = blk%36, tI = t2/6, tJ = t2%6;
  int tr = (threadIdx.x/16)*4, tc = (threadIdx.x%16)*4;
  double acc[4][4];
#pragma unroll
  for (int i = 0; i < 4; i++)
#pragma unroll
    for (int j = 0; j < 4; j++) acc[i][j] = 0.0;
  for (int ss = 0; ss < 512; ss++) {
    int s = kg*512 + ss;
    size_t base = (size_t)s*9216;
    for (int l = threadIdx.x; l < 1536; l += TPB) {
      int row = l/24, w = l-row*24;
      aS[row*25+w] = sv[base + (size_t)tI*1536 + l];
      bS[row*25+w] = sv[base + (size_t)tJ*1536 + l];
    }
    __syncthreads();
    for (int w = 0; w < 24; w++) {
      double a0 = aS[(tr+0)*25+w], a1 = aS[(tr+1)*25+w], a2 = aS[(tr+2)*25+w], a3 = aS[(tr+3)*25+w];
      double b0 = bS[(tc+0)*25+w], b1 = bS[(tc+1)*25+w], b2 = bS[(tc+2)*25+w], b3 = bS[(tc+3)*25+w];
      acc[0][0]+=a0*b0; acc[0][1]+=a0*b1; acc[0][2]+=a0*b2; acc[0][3]+=a0*b3;
      acc[1][0]+=a1*b0; acc[1][1]+=a1*b1; acc[1][2]+=a1*b2; acc[1][3]+=a1*b3;
      acc[2][0]+=a2*b0; acc[2][1]+=a2*b1; acc[2][2]+=a2*b2; acc[2][3]+=a2*b3;
      acc[3][0]+=a3*b0; acc[3][1]+=a3*b1; acc[3][2]+=a3*b2; acc[3][3]+=a3*b3;
    }
    __syncthreads();
  }
  for (int i = 0; i < 4; i++)
    for (int j = 0; j < 4; j++)
      parts[(size_t)kg*147456 + (size_t)(tI*64+tr+i)*384 + (tJ*64+tc+j)] = acc[i][j];
}
__global__ __launch_bounds__(TPB) void k_g3p(const float* __restrict__ sv, double* parts){
  __shared__ float slab[9216];
  int b = blockIdx.x;
  double acc[3]; int w1s[3], w2s[3];
#pragma unroll
  for (int k = 0; k < 3; k++) { int e = threadIdx.x + k*TPB; acc[k] = 0.0; w1s[k] = e/24; w2s[k] = e%24; }
  for (int q = 0; q < 24; q++) {
    int s = b*24 + q;
    size_t base = (size_t)s*9216;
    for (int l = threadIdx.x; l < 9216; l += TPB) slab[l] = sv[base + l];
    __syncthreads();
#pragma unroll
    for (int k = 0; k < 3; k++) {
      int e = threadIdx.x + k*TPB;
      if (e < 576) {
        double sacc = 0.0;
#pragma unroll 4
        for (int p = 0; p < 384; p++) sacc += (double)slab[p*24+w1s[k]]*(double)slab[p*24+w2s[k]];
        acc[k] += sacc;
      }
    }
    __syncthreads();
  }
  for (int k = 0; k < 3; k++) {
    int e = threadIdx.x + k*TPB;
    if (e < 576) parts[(size_t)b*576 + e] = acc[k];
  }
}
__global__ __launch_bounds__(TPB) void k_reduce(double* out, const double* parts, int np, int len){
  int i = blockIdx.x*TPB + threadIdx.x;
  if (i >= len) return;
  double acc = 0.0;
#pragma unroll 4
  for (int p = 0; p < np; p++) acc += parts[(size_t)p*len + i];
  out[i] = acc;
}

__global__ __launch_bounds__(TPB) void k_c2sv(const float* __restrict__ sv,
                                              const double* __restrict__ U2,
                                              double* __restrict__ out){
  __shared__ float slab[9216];
  __shared__ double u2s[2304];
  for (int l = threadIdx.x; l < 2304; l += TPB) u2s[l] = U2[l];
  size_t base = (size_t)blockIdx.x*9216;
  for (int l = threadIdx.x; l < 9216; l += TPB) slab[l] = sv[base + l];
  __syncthreads();
  int t = threadIdx.x;
  if (t < 144) {
    int j = t/24, w = t%24;
    double acc = 0.0;
#pragma unroll 8
    for (int p = 0; p < 384; p++) acc += (double)slab[p*24+w]*u2s[p*6+j];
    out[(size_t)blockIdx.x*144 + t] = acc;
  }
}
__global__ __launch_bounds__(TPB) void k_c1sv(const float* __restrict__ sv,
                                              const double* __restrict__ U1,
                                              double* __restrict__ out){
  int t = blockIdx.x*TPB + threadIdx.x;
  if (t >= 294912) return;
  int c = t/9216; int rem = t%9216; int p = rem/24; int w = rem%24;
  double a0 = 0.0, a1 = 0.0;
#pragma unroll 4
  for (int d = 0; d < 96; d++) {
    double v = (double)sv[(((size_t)c*96+d)*384+p)*24 + w];
    a0 += v*U1[d*2+0];
    a1 += v*U1[d*2+1];
  }
  out[((size_t)c*2+0)*9216 + p*24 + w] = a0;
  out[((size_t)c*2+1)*9216 + p*24 + w] = a1;
}
__global__ __launch_bounds__(TPB) void k_contract4(const double* __restrict__ in,
                                                   const double* __restrict__ U,
                                                   double* __restrict__ out,
                                                   int s0, int s1, int s2, int s3,
                                                   int ax, int r){
  int os0 = (ax==0)?r:s0, os1 = (ax==1)?r:s1, os2 = (ax==2)?r:s2, os3 = (ax==3)?r:s3;
  long tot = (long)os0*os1*os2*os3;
  long str3 = 1, str2 = s3, str1 = (long)s2*s3, str0 = (long)s1*s2*s3;
  for (long idx = blockIdx.x*(long)TPB + threadIdx.x; idx < tot; idx += (long)gridDim.x*TPB) {
    long t = idx;
    int i3 = (int)(t % os3); t /= os3;
    int i2 = (int)(t % os2); t /= os2;
    int i1 = (int)(t % os1); int i0 = (int)(t/os1);
    int j;
    long base; long st; int sa;
    if (ax == 0)      { j = i0; base = (long)i1*str1 + i2*str2 + i3; st = str0; sa = s0; }
    else if (ax == 1) { j = i1; base = (long)i0*str0 + i2*str2 + i3; st = str1; sa = s1; }
    else if (ax == 2) { j = i2; base = (long)i0*str0 + i1*str1 + i3; st = str2; sa = s2; }
    else              { j = i3; base = (long)i0*str0 + i1*str1 + i2*str2; st = str3; sa = s3; }
    double acc = 0.0;
#pragma unroll 4
    for (int c = 0; c < sa; c++) acc += in[base + (long)c*st] * U[c*r + j];
    out[idx] = acc;
  }
}

__global__ __launch_bounds__(TPB) void k_gram_sw0(const double* __restrict__ y, double* G){
  for (int e = threadIdx.x; e < 576; e += TPB) {
    int c1 = e/24, c2 = e%24;
    double acc = 0.0;
#pragma unroll 4
    for (int i = 0; i < 32; i++) acc += y[i*24+c1]*y[i*24+c2];
    G[e] = acc;
  }
}
__global__ __launch_bounds__(TPB) void k_gram_sw1(const double* __restrict__ y, double* G){
  for (int e = threadIdx.x; e < 9216; e += TPB) {
    int d1 = e/96, d2 = e%96;
    double acc = 0.0;
#pragma unroll 2
    for (int a = 0; a < 8; a++)
#pragma unroll
      for (int ee = 0; ee < 6; ee++)
#pragma unroll
        for (int m = 0; m < 2; m++)
          acc += y[(((size_t)a*96+d1)*6+ee)*2+m]*y[(((size_t)a*96+d2)*6+ee)*2+m];
    G[e] = acc;
  }
}
__global__ __launch_bounds__(TPB) void k_gram_sw2(const double* __restrict__ y, double* G){
  for (int e = threadIdx.x; e < 1024; e += TPB) {
    int q1 = e/32, q2 = e%32;
    double acc = 0.0;
#pragma unroll 4
    for (int p = 0; p < 384; p++)
      acc += y[(size_t)(q1>>1)*768 + p*2 + (q1&1)]*y[(size_t)(q2>>1)*768 + p*2 + (q2&1)];
    G[e] = acc;
  }
}
__global__ __launch_bounds__(TPB) void k_gram_sw3(const double* __restrict__ y, double* G){
  for (int e = threadIdx.x; e < 576; e += TPB) {
    int w1 = e/24, w2 = e%24;
    double acc = 0.0;
#pragma unroll 2
    for (int a = 0; a < 8; a++)
#pragma unroll
      for (int j = 0; j < 2; j++)
#pragma unroll
        for (int ee = 0; ee < 6; ee++)
          acc += y[(((size_t)a*2+j)*6+ee)*24+w1]*y[(((size_t)a*2+j)*6+ee)*24+w2];
    G[e] = acc;
  }
}

__global__ __launch_bounds__(TPB) void k_fact_sq(double* U, const double* Z, int n, int r){
  int t = blockIdx.x*TPB + threadIdx.x;
  if (t >= n*r) return;
  int i = t/r, j = t%r;
  U[t] = Z[(size_t)(n-1-j)*n + i];
}
__global__ __launch_bounds__(TPB) void k_factT0(double* U0, const double* y,
                                                const double* Z, const double* D){
  int t = threadIdx.x;
  if (t >= 256) return;
  int i = t/8, j = t%8;
  int col = 23-j;
  double acc = 0.0;
#pragma unroll 4
  for (int c = 0; c < 24; c++) acc += y[i*24+c]*Z[(size_t)col*24+c];
  U0[t] = acc / sqrt(fmax(D[col], 1e-12));
}
__global__ __launch_bounds__(TPB) void k_factT2(double* U2, const double* y,
                                                const double* Z, const double* D){
  int t = blockIdx.x*TPB + threadIdx.x;
  if (t >= 2304) return;
  int p = t/6, j = t%6;
  int col = 31-j;
  double acc = 0.0;
#pragma unroll 4
  for (int q = 0; q < 32; q++)
    acc += y[(size_t)(q>>1)*768 + p*2 + (q&1)]*Z[(size_t)col*32+q];
  U2[t] = acc / sqrt(fmax(D[col], 1e-12));
}

__global__ __launch_bounds__(TPB) void k_tail(const double* __restrict__ core,
                                              const float* __restrict__ action,
                                              const float* __restrict__ wa,
                                              const float* __restrict__ ba,
                                              const float* __restrict__ wq,
                                              const float* __restrict__ bq,
                                              float* __restrict__ out){
  __shared__ double s[TPB];
  int t = threadIdx.x;
  double v = 0.0;
  if (t < 192) {
    double av = 0.0;
#pragma unroll 4
    for (int i = 0; i < 96; i++) av += (double)action[i]*(double)wa[t*96+i];
    av += (double)ba[t];
    if (av < 0.0) av = 0.0;
    double sav = core[t] + av;
    if (sav < 0.0) sav = 0.0;
    v = sav * (double)wq[t];
  }
  s[t] = v; __syncthreads();
  for (int st = 128; st > 0; st >>= 1) { if (t < st) s[t] += s[t+st]; __syncthreads(); }
  if (t == 0) out[0] = (float)(s[0] + (double)bq[0]);
}
__global__ void k_fail(float* out){ out[0] = 1234.5f; }

// ============================ host launcher ============================
extern "C" void kernel_launch(void* const* d_in, const int* in_sizes, int n_in,
                              void* d_out, int out_size, void* d_ws, size_t ws_size,
                              hipStream_t stream){
  (void)in_sizes; (void)n_in; (void)out_size;
  const float* state  = (const float*)d_in[0];
  const float* action = (const float*)d_in[1];
  const float* conv_w = (const float*)d_in[2];
  const float* conv_b = (const float*)d_in[3];
  const float* wa     = (const float*)d_in[4];
  const float* ba     = (const float*)d_in[5];
  const float* wq     = (const float*)d_in[6];
  const float* bq     = (const float*)d_in[7];
  float* outp = (float*)d_out;

  char* ws = (char*)d_ws;
  size_t off = 0;
  auto alloc = [&](size_t bytes){ size_t o = off; off = (off + bytes + 255) & ~(size_t)255; return o; };
  size_t o_sv   = alloc(28311552ull*4);
  size_t o_A    = alloc(589824ull*8);
  size_t o_B    = alloc(49152ull*8);
  size_t o_C    = alloc(12288ull*8);
  size_t o_U0   = alloc(32*8*8);
  size_t o_U1   = alloc(96*2*8);
  size_t o_U2   = alloc(384*6*8);
  size_t o_U3   = alloc(24*2*8);
  size_t o_core = alloc(192*8);
  size_t o_G    = alloc(384ull*384*8);
  size_t o_Z    = alloc(384ull*384*8);
  size_t o_D    = alloc(384*8);
  size_t o_Tau  = alloc(384*8);
  size_t o_Sd   = alloc(384*8);
  size_t o_Se   = alloc(384*8);
  size_t o_Ixq  = alloc(384*4);
  size_t o_schd = alloc(8192);
  size_t o_pts  = alloc(7864320ull);   // gram partials | eigh scratch alias (GWRK_DBL doubles)
  if (off > ws_size) { hipLaunchKernelGGL(k_fail, dim3(1), dim3(1), 0, stream, outp); return; }

  float*  sv   = (float*)(ws + o_sv);
  double* bufA = (double*)(ws + o_A);
  double* bufB = (double*)(ws + o_B);
  double* bufC = (double*)(ws + o_C);
  double* U0   = (double*)(ws + o_U0);
  double* U1   = (double*)(ws + o_U1);
  double* U2   = (double*)(ws + o_U2);
  double* U3   = (double*)(ws + o_U3);
  double* core = (double*)(ws + o_core);
  double* G    = (double*)(ws + o_G);
  double* Zb   = (double*)(ws + o_Z);
  double* Db   = (double*)(ws + o_D);
  double* gTau = (double*)(ws + o_Tau);
  double* gSd  = (double*)(ws + o_Sd);
  double* gSe  = (double*)(ws + o_Se);
  int*    gIxq = (int*)(ws + o_Ixq);
  Sched*  schd = (Sched*)(ws + o_schd);
  double* parts = (double*)(ws + o_pts);
  double* gwrk  = parts;

  auto eigh = [&](int n){
    if (n <= 96) {
      size_t shb = (size_t)2*n*n*8;
      hipLaunchKernelGGL((k_eigh_small<TPB,96>), dim3(1), dim3(TPB), shb, stream,
                         n, G, Zb, Db, gwrk);
    } else {
      hipLaunchKernelGGL((k_sytd2_big<384>), dim3(1), dim3(384), 0, stream,
                         n, G, gSd, gSe, gTau);
      hipLaunchKernelGGL((k_stedc_pre<1024>), dim3(1), dim3(1024), 0, stream,
                         n, Zb, gwrk, gSd, gSe, gIxq, schd);
      for (int L = 0; L < MLEV; L++)
        hipLaunchKernelGGL((k_stedc_merge<512>), dim3(MAXTASK), dim3(512), 0, stream,
                           n, L, Zb, gwrk, gSd, gSe, gIxq, schd);
      hipLaunchKernelGGL((k_stedc_fin<1024>), dim3(1), dim3(1024), 0, stream,
                         n, Zb, Db, gwrk, gSd, gIxq, schd);
      // only top-8 eigenvector columns are consumed downstream (k_fact_sq r=6)
      hipLaunchKernelGGL(k_ormtr_big, dim3(1), dim3(256), 0, stream,
                         n, G, Zb, gTau, n - OB_COLS);
    }
  };

  hipLaunchKernelGGL(k_conv, dim3(110592), dim3(TPB), 0, stream, state, conv_w, conv_b, sv);

  // ---- init HOSVD factors ----
  hipLaunchKernelGGL(k_g0p, dim3(288), dim3(TPB), 0, stream, sv, parts);
  hipLaunchKernelGGL(k_reduce, dim3(4), dim3(TPB), 0, stream, G, parts, 288, 1024);
  eigh(32);
  hipLaunchKernelGGL(k_fact_sq, dim3(1), dim3(TPB), 0, stream, U0, Zb, 32, 8);

  hipLaunchKernelGGL(k_g1p, dim3(32), dim3(TPB), 0, stream, sv, parts);
  hipLaunchKernelGGL(k_reduce, dim3(36), dim3(TPB), 0, stream, G, parts, 32, 9216);
  eigh(96);
  hipLaunchKernelGGL(k_fact_sq, dim3(1), dim3(TPB), 0, stream, U1, Zb, 96, 2);

  hipLaunchKernelGGL(k_g2p, dim3(G2_NKG*36), dim3(TPB), 0, stream, sv, parts);
  hipLaunchKernelGGL(k_reduce, dim3(576), dim3(TPB), 0, stream, G, parts, G2_NKG, 147456);
  eigh(384);
  hipLaunchKernelGGL(k_fact_sq, dim3(9), dim3(TPB), 0, stream, U2, Zb, 384, 6);

  hipLaunchKernelGGL(k_g3p, dim3(128), dim3(TPB), 0, stream, sv, parts);
  hipLaunchKernelGGL(k_reduce, dim3(3), dim3(TPB), 0, stream, G, parts, 128, 576);
  eigh(24);
  hipLaunchKernelGGL(k_fact_sq, dim3(1), dim3(TPB), 0, stream, U3, Zb, 24, 2);

  // ---- HOOI sweeps (c2sv deduped: n=0/n=1 share bufA; core reuses s=4 n=3 bufA/bufB) ----
  for (int s = 0; s < 5; s++) {
    // shared U2-projection for n=0 and n=1
    hipLaunchKernelGGL(k_c2sv, dim3(3072), dim3(TPB), 0, stream, sv, U2, bufA);
    // n=0 : project order [2,1,3]
    hipLaunchKernelGGL(k_contract4, dim3(36), dim3(TPB), 0, stream, bufA, U1, bufB, 32,96,6,24, 1, 2);
    hipLaunchKernelGGL(k_contract4, dim3(3),  dim3(TPB), 0, stream, bufB, U3, bufC, 32,2,6,24, 3, 2);
    hipLaunchKernelGGL(k_gram_sw0, dim3(1), dim3(TPB), 0, stream, bufC, G);
    eigh(24);
    hipLaunchKernelGGL(k_factT0, dim3(1), dim3(TPB), 0, stream, U0, bufC, Zb, Db);
    // n=1 : [2,3,0] (bufA reused — U2 unchanged)
    hipLaunchKernelGGL(k_contract4, dim3(144), dim3(TPB), 0, stream, bufA, U3, bufB, 32,96,6,24, 3, 2);
    hipLaunchKernelGGL(k_contract4, dim3(36),  dim3(TPB), 0, stream, bufB, U0, bufC, 32,96,6,2, 0, 8);
    hipLaunchKernelGGL(k_gram_sw1, dim3(1), dim3(TPB), 0, stream, bufC, G);
    eigh(96);
    hipLaunchKernelGGL(k_fact_sq, dim3(1), dim3(TPB), 0, stream, U1, Zb, 96, 2);
    // n=2 : [1,3,0]
    hipLaunchKernelGGL(k_c1sv, dim3(1152), dim3(TPB), 0, stream, sv, U1, bufA);
    hipLaunchKernelGGL(k_contract4, dim3(192), dim3(TPB), 0, stream, bufA, U3, bufB, 32,2,384,24, 3, 2);
    hipLaunchKernelGGL(k_contract4, dim3(48),  dim3(TPB), 0, stream, bufB, U0, bufC, 32,2,384,2, 0, 8);
    hipLaunchKernelGGL(k_gram_sw2, dim3(1), dim3(TPB), 0, stream, bufC, G);
    eigh(32);
    hipLaunchKernelGGL(k_factT2, dim3(9), dim3(TPB), 0, stream, U2, bufC, Zb, Db);
    // n=3 : [2,1,0]
    hipLaunchKernelGGL(k_c2sv, dim3(3072), dim3(TPB), 0, stream, sv, U2, bufA);
    hipLaunchKernelGGL(k_contract4, dim3(36), dim3(TPB), 0, stream, bufA, U1, bufB, 32,96,6,24, 1, 2);
    hipLaunchKernelGGL(k_contract4, dim3(9),  dim3(TPB), 0, stream, bufB, U0, bufC, 32,2,6,24, 0, 8);
    hipLaunchKernelGGL(k_gram_sw3, dim3(1), dim3(TPB), 0, stream, bufC, G);
    eigh(24);
    hipLaunchKernelGGL(k_fact_sq, dim3(1), dim3(TPB), 0, stream, U3, Zb, 24, 2);
  }

  // ---- core : [2,1,3,0] — bufA (c2sv with same U2) and bufB (contract U1) are
  // bitwise-identical to sweep-5 n=3's; reuse them directly.
  hipLaunchKernelGGL(k_contract4, dim3(3),  dim3(TPB), 0, stream, bufB, U3, bufC, 32,2,6,24, 3, 2);
  hipLaunchKernelGGL(k_contract4, dim3(1),  dim3(TPB), 0, stream, bufC, U0, core, 32,2,6,2, 0, 8);

  hipLaunchKernelGGL(k_tail, dim3(1), dim3(TPB), 0, stream, core, action, wa, ba, wq, bq, outp);
}